// Round 4
// baseline (391.303 us; speedup 1.0000x reference)
//
#include <hip/hip_runtime.h>
#include <hip/hip_bf16.h>

typedef float v4f __attribute__((ext_vector_type(4)));
typedef short bf8 __attribute__((ext_vector_type(8)));  // 8 bf16 in 4 VGPRs
typedef unsigned short u16;

constexpr float W_C_ = 0.23570226039551584f;  // sqrt(2/(9*4))
constexpr float W_L_ = 0.5773502691896258f;   // sqrt(1/3)

__device__ __forceinline__ u16 f2bf(float f) {  // RNE f32->bf16
  unsigned u = __float_as_uint(f);
  return (u16)((u + 0x7FFFu + ((u >> 16) & 1u)) >> 16);
}
__device__ __forceinline__ float bf2f(u16 h) {
  return __uint_as_float(((unsigned)h) << 16);
}
__device__ __forceinline__ float dot4(v4f a, v4f b) {
  return a.x * b.x + a.y * b.y + a.z * b.z + a.w * b.w;
}

// ---------------------------------------------------------------------------
// f32 -> bf16 elementwise (n8 = n/8 chunks)
// ---------------------------------------------------------------------------
__global__ __launch_bounds__(256) void convert_bf(const float* __restrict__ src,
                                                  u16* __restrict__ dst, int n8) {
  int idx = blockIdx.x * 256 + threadIdx.x;
  if (idx < n8) {
    v4f a = ((const v4f*)src)[idx * 2];
    v4f b = ((const v4f*)src)[idx * 2 + 1];
    bf8 o;
    o[0] = (short)f2bf(a.x); o[1] = (short)f2bf(a.y);
    o[2] = (short)f2bf(a.z); o[3] = (short)f2bf(a.w);
    o[4] = (short)f2bf(b.x); o[5] = (short)f2bf(b.y);
    o[6] = (short)f2bf(b.z); o[7] = (short)f2bf(b.w);
    ((bf8*)dst)[idx] = o;
  }
}

// ---------------------------------------------------------------------------
// Pre-fragment W[K][N] (f32, optional scale) into MFMA B-fragment order.
// ---------------------------------------------------------------------------
__global__ __launch_bounds__(256) void wfrag_k(const float* __restrict__ W,
                                               u16* __restrict__ frag,
                                               int K, int N, float scale) {
  __shared__ float Ws[32 * 384];
  const int ks = blockIdx.x, k0 = ks * 32, t = threadIdx.x;
  const int NTfull = (N + 15) >> 4;
  for (int n0 = 0; n0 < N; n0 += 384) {
    int PN = N - n0; if (PN > 384) PN = 384;
    __syncthreads();
    for (int idx = t; idx < 32 * PN; idx += 256) {
      int r = idx / PN, c = idx - r * PN;
      Ws[r * PN + c] = W[(size_t)(k0 + r) * N + n0 + c];
    }
    __syncthreads();
    int NTp = (PN + 15) >> 4;
    for (int c = t; c < NTp * 64; c += 256) {
      int nt = c >> 6, l = c & 63;
      int col = nt * 16 + (l & 15);
      bf8 o;
#pragma unroll
      for (int e = 0; e < 8; e++) {
        int rr = (l >> 4) * 8 + e;
        float f = (col < PN) ? Ws[rr * PN + col] * scale : 0.f;
        o[e] = (short)f2bf(f);
      }
      ((bf8*)frag)[((size_t)ks * NTfull + (n0 >> 4) + nt) * 64 + l] = o;
    }
  }
}

// ---------------------------------------------------------------------------
// f32 GEMM, BM=64 BN=32 BK=32, micro 4x2 (point projections, f32 precision).
// ---------------------------------------------------------------------------
__global__ __launch_bounds__(256) void gemm_f32(
    const float* __restrict__ A, const float* __restrict__ B,
    float* __restrict__ C, int M, int N, int K) {
  __shared__ float AsT[32][68];
  __shared__ float Bs[32][36];
  const int bi = blockIdx.y * 64, bj = blockIdx.x * 32;
  const int t = threadIdx.x, ty = t >> 4, tx = t & 15;
  v4f acc0 = {0.f, 0.f, 0.f, 0.f}, acc1 = {0.f, 0.f, 0.f, 0.f};
  for (int k0 = 0; k0 < K; k0 += 32) {
#pragma unroll
    for (int q = 0; q < 2; q++) {
      int idx = t + 256 * q;
      int row = idx >> 3, c4 = idx & 7;
      v4f av = *(const v4f*)(A + (size_t)(bi + row) * K + k0 + c4 * 4);
      AsT[c4 * 4 + 0][row] = av.x;
      AsT[c4 * 4 + 1][row] = av.y;
      AsT[c4 * 4 + 2][row] = av.z;
      AsT[c4 * 4 + 3][row] = av.w;
    }
    {
      int r = t >> 3, c4 = t & 7;
      *(v4f*)&Bs[r][c4 * 4] = *(const v4f*)(B + (size_t)(k0 + r) * N + bj + c4 * 4);
    }
    __syncthreads();
#pragma unroll
    for (int kk = 0; kk < 32; kk++) {
      v4f a = *(const v4f*)&AsT[kk][ty * 4];
      float b0 = Bs[kk][tx * 2], b1 = Bs[kk][tx * 2 + 1];
      acc0 += a * b0;
      acc1 += a * b1;
    }
    __syncthreads();
  }
#pragma unroll
  for (int e = 0; e < 4; e++) {
    int row = bi + ty * 4 + e;
    C[(size_t)row * N + bj + tx * 2] = acc0[e];
    C[(size_t)row * N + bj + tx * 2 + 1] = acc1[e];
  }
}

// ---------------------------------------------------------------------------
// bf16 MFMA GEMM (pre-fragmented B direct from global), BM=64 BN=32.
// ---------------------------------------------------------------------------
__global__ __launch_bounds__(256) void mfma_gemm(
    const u16* __restrict__ Abf, const u16* __restrict__ Bfrag,
    const float* __restrict__ bias, float* __restrict__ C,
    int M, int N, int K, int ldc) {
  __shared__ u16 As[64 * 32];
  const int t = threadIdx.x, w = t >> 6, l = t & 63;
  const int bi = blockIdx.y * 64, nt0 = blockIdx.x * 2;
  const int NT = N >> 4, KS = K >> 5;
  v4f acc0 = {0.f, 0.f, 0.f, 0.f}, acc1 = {0.f, 0.f, 0.f, 0.f};
  const int srow = t >> 2, sc = t & 3;
  const int wslot = (sc ^ (srow & 3)) * 8;
  const bf8* Bf = (const bf8*)Bfrag;

  bf8 areg = *(const bf8*)(Abf + (size_t)(bi + srow) * K + sc * 8);
  bf8 b0 = Bf[(size_t)(0 * NT + nt0) * 64 + l];
  bf8 b1 = Bf[(size_t)(0 * NT + nt0 + 1) * 64 + l];
  const int rdoff = (w * 16 + (l & 15)) * 32 + (((l >> 4) ^ (l & 3)) * 8);
  for (int ks = 0; ks < KS; ks++) {
    *(bf8*)&As[srow * 32 + wslot] = areg;
    bf8 an, bn0, bn1;
    if (ks + 1 < KS) {
      an = *(const bf8*)(Abf + (size_t)(bi + srow) * K + (ks + 1) * 32 + sc * 8);
      bn0 = Bf[(size_t)((ks + 1) * NT + nt0) * 64 + l];
      bn1 = Bf[(size_t)((ks + 1) * NT + nt0 + 1) * 64 + l];
    }
    __syncthreads();
    bf8 af = *(const bf8*)&As[rdoff];
    acc0 = __builtin_amdgcn_mfma_f32_16x16x32_bf16(af, b0, acc0, 0, 0, 0);
    acc1 = __builtin_amdgcn_mfma_f32_16x16x32_bf16(af, b1, acc1, 0, 0, 0);
    __syncthreads();
    areg = an; b0 = bn0; b1 = bn1;
  }
  int col0 = nt0 * 16 + (l & 15), col1 = col0 + 16;
  float bb0 = bias ? bias[col0] : 0.f;
  float bb1 = bias ? bias[col1] : 0.f;
#pragma unroll
  for (int r = 0; r < 4; r++) {
    int row = bi + w * 16 + (l >> 4) * 4 + r;
    C[(size_t)row * ldc + col0] = acc0[r] + bb0;
    C[(size_t)row * ldc + col1] = acc1[r] + bb1;
  }
}

// ---------------------------------------------------------------------------
// Prep: reshape projections, apply frames, build all per-residue buffers.
// qbuf [n][h*16+c]; kbuf [n][h*16+c]; v2buf [n][h*40+e]; qgbuf/kgbuf
// [n][h*12+e]; sqbuf/skbuf [n][12].
// ---------------------------------------------------------------------------
__global__ __launch_bounds__(256) void prep_kernel(
    const float* __restrict__ projQKV, const float* __restrict__ projQKP,
    const float* __restrict__ projVP, const float* __restrict__ fR,
    const float* __restrict__ ft,
    float* __restrict__ qbuf, float* __restrict__ kbuf, float* __restrict__ v2buf,
    float* __restrict__ qgbuf, float* __restrict__ kgbuf,
    float* __restrict__ sqbuf, float* __restrict__ skbuf) {
  const int n = blockIdx.x, t = threadIdx.x;
  __shared__ float R[9], tt[3];
  __shared__ float qgL[144], kgL[144];
  if (t < 9) R[t] = fR[n * 9 + t];
  if (t < 3) tt[t] = ft[n * 3 + t];
  __syncthreads();
  const float* rQKV = projQKV + (size_t)n * 576;
  const float* rQKP = projQKP + (size_t)n * 288;
  const float* rVP = projVP + (size_t)n * 288;
  if (t < 192) {
    int h = t >> 4, c = t & 15;
    qbuf[(size_t)n * 192 + t] = rQKV[c * 12 + h];
    kbuf[(size_t)n * 192 + t] = rQKV[192 + c * 12 + h];
    v2buf[(size_t)n * 480 + h * 40 + c] = rQKV[384 + c * 12 + h];
  }
  if (t < 144) {
    int e = t / 12, h = t % 12;
    int p = e / 3, x = e % 3;
    float aq = tt[x], ak = tt[x];
#pragma unroll
    for (int y = 0; y < 3; y++) {
      float r = R[x * 3 + y];
      aq += r * rQKP[p * 36 + y * 12 + h];
      ak += r * rQKP[144 + p * 36 + y * 12 + h];
    }
    qgL[h * 12 + e] = aq;
    kgL[h * 12 + e] = ak;
    qgbuf[(size_t)n * 144 + h * 12 + e] = aq;
    kgbuf[(size_t)n * 144 + h * 12 + e] = ak;
  }
  for (int idx = t; idx < 288; idx += 256) {
    int e = idx / 12, h = idx % 12;
    int p = e / 3, x = e % 3;
    float a = tt[x];
#pragma unroll
    for (int y = 0; y < 3; y++) a += R[x * 3 + y] * rVP[p * 36 + y * 12 + h];
    v2buf[(size_t)n * 480 + h * 40 + 16 + e] = a;
  }
  __syncthreads();
  if (t < 12) {
    float s = 0.f;
#pragma unroll
    for (int e = 0; e < 12; e++) { float v = qgL[t * 12 + e]; s += v * v; }
    sqbuf[n * 12 + t] = s;
  } else if (t < 24) {
    int h = t - 12;
    float s = 0.f;
#pragma unroll
    for (int e = 0; e < 12; e++) { float v = kgL[h * 12 + e]; s += v * v; }
    skbuf[n * 12 + h] = s;
  }
}

// ---------------------------------------------------------------------------
// FUSED flash IPA: grid (4 j-chunks, 768 i). Reads pair ONCE. Per 64-j tile:
//  A: pair f32 regs -> bf16 swizzled LDS (prefetch next tile)
//  B: 4x MFMA -> W_L * pair-bias (f32)
//  C: VALU adds qk + point-dist terms (k-side straight from L2, f32)
//  D: tile max + online softmax; writes tile-referenced p (bf16) + tile max
//  E: all threads accumulate o_pair from bf16 LDS tile
// Tail: chunk partials (o_pair, m, l) to global.
// ---------------------------------------------------------------------------
__global__ __launch_bounds__(256) void ipa_fused(
    const float* __restrict__ pair, const u16* __restrict__ WbFrag,
    const float* __restrict__ gamma,
    const float* __restrict__ qbuf, const float* __restrict__ kbuf,
    const float* __restrict__ qgbuf, const float* __restrict__ kgbuf,
    const float* __restrict__ sqbuf, const float* __restrict__ skbuf,
    u16* __restrict__ pW, float* __restrict__ mTW,
    float* __restrict__ opP, float* __restrict__ mlP) {
  const int ch = blockIdx.x, i = blockIdx.y, t = threadIdx.x;
  const int w = t >> 6, l = t & 63;
  __shared__ u16 pS[64 * 128];
  __shared__ float lgL[64 * 14];
  __shared__ float pL[64 * 12];
  __shared__ float qL[192], qgL[144];
  __shared__ float c1L[12], c2L[12], mL[12], lL[12], rL[12];

  // init
  if (t < 192) qL[t] = qbuf[(size_t)i * 192 + t];
  if (t < 144) qgL[t] = qgbuf[(size_t)i * 144 + t];
  if (t < 12) {
    float g = gamma[t];
    float hw = fmaxf(g, 0.f) + log1pf(expf(-fabsf(g)));
    c1L[t] = W_L_ * W_C_ * hw;
    c2L[t] = -0.5f * c1L[t] * sqbuf[i * 12 + t];
    mL[t] = -1e30f;
    lL[t] = 0.f;
  }
  bf8 wb[4];
  const bf8* Wf = (const bf8*)WbFrag;
#pragma unroll
  for (int ks = 0; ks < 4; ks++) wb[ks] = Wf[ks * 64 + l];

  // prefetch tile 0 pair rows
  v4f pr[8];
  {
    const float* pg = pair + ((size_t)i * 768 + ch * 192) * 128;
#pragma unroll
    for (int it = 0; it < 4; it++) {
      int idx = t + 256 * it;
      int j = idx >> 4, c = idx & 15;
      pr[2 * it] = *(const v4f*)(pg + j * 128 + c * 8);
      pr[2 * it + 1] = *(const v4f*)(pg + j * 128 + c * 8 + 4);
    }
  }
  float opacc[6];
#pragma unroll
  for (int k = 0; k < 6; k++) opacc[k] = 0.f;
  const int d = t & 127, hb6 = (t >> 7) * 6;
  const bool lohalf = (t < 128);
  __syncthreads();

  for (int tile = 0; tile < 3; tile++) {
    const int jg0 = ch * 192 + tile * 64;
    // ---- A: write swizzled bf16 tile, prefetch next ----
#pragma unroll
    for (int it = 0; it < 4; it++) {
      int idx = t + 256 * it;
      int j = idx >> 4, c = idx & 15;
      v4f x0 = pr[2 * it], x1 = pr[2 * it + 1];
      bf8 pk;
      pk[0] = (short)f2bf(x0.x); pk[1] = (short)f2bf(x0.y);
      pk[2] = (short)f2bf(x0.z); pk[3] = (short)f2bf(x0.w);
      pk[4] = (short)f2bf(x1.x); pk[5] = (short)f2bf(x1.y);
      pk[6] = (short)f2bf(x1.z); pk[7] = (short)f2bf(x1.w);
      *(bf8*)&pS[j * 128 + ((c ^ (j & 15)) * 8)] = pk;
    }
    if (tile < 2) {
      const float* pg = pair + ((size_t)i * 768 + jg0 + 64) * 128;
#pragma unroll
      for (int it = 0; it < 4; it++) {
        int idx = t + 256 * it;
        int j = idx >> 4, c = idx & 15;
        pr[2 * it] = *(const v4f*)(pg + j * 128 + c * 8);
        pr[2 * it + 1] = *(const v4f*)(pg + j * 128 + c * 8 + 4);
      }
    }
    __syncthreads();
    // ---- B: bias MFMA (result = W_L * b, f32) ----
    {
      v4f acc = {0.f, 0.f, 0.f, 0.f};
#pragma unroll
      for (int ks = 0; ks < 4; ks++) {
        int slot = (ks * 4 + (l >> 4)) ^ (l & 15);
        bf8 af = *(const bf8*)&pS[(w * 16 + (l & 15)) * 128 + slot * 8];
        acc = __builtin_amdgcn_mfma_f32_16x16x32_bf16(af, wb[ks], acc, 0, 0, 0);
      }
      int h = l & 15;
      if (h < 12) {
#pragma unroll
        for (int r = 0; r < 4; r++)
          lgL[(w * 16 + (l >> 4) * 4 + r) * 14 + h] = acc[r];
      }
    }
    __syncthreads();
    // ---- C: qk + point-dist (f32, k-side from L2) ----
    {
      const int j = t >> 2, hg = t & 3;
      const int jg = jg0 + j;
#pragma unroll
      for (int hh = 0; hh < 3; hh++) {
        int h = hg * 3 + hh;
        const v4f* kk = (const v4f*)(kbuf + (size_t)jg * 192 + h * 16);
        const v4f* qq = (const v4f*)&qL[h * 16];
        float qk = dot4(kk[0], qq[0]) + dot4(kk[1], qq[1]) +
                   dot4(kk[2], qq[2]) + dot4(kk[3], qq[3]);
        const v4f* kg = (const v4f*)(kgbuf + (size_t)jg * 144 + h * 12);
        const v4f* qg = (const v4f*)&qgL[h * 12];
        float cr = dot4(kg[0], qg[0]) + dot4(kg[1], qg[1]) + dot4(kg[2], qg[2]);
        float sk = skbuf[(size_t)jg * 12 + h];
        lgL[j * 14 + h] += 0.25f * W_L_ * qk + c1L[h] * (cr - 0.5f * sk) + c2L[h];
      }
    }
    __syncthreads();
    // ---- D: tile softmax + online update; write tile-ref p to global ----
    if (t < 192) {
      const int h = t >> 4, jj = t & 15;
      float lg0 = lgL[(jj * 4 + 0) * 14 + h];
      float lg1 = lgL[(jj * 4 + 1) * 14 + h];
      float lg2 = lgL[(jj * 4 + 2) * 14 + h];
      float lg3 = lgL[(jj * 4 + 3) * 14 + h];
      float tmax = fmaxf(fmaxf(lg0, lg1), fmaxf(lg2, lg3));
#pragma unroll
      for (int m = 1; m < 16; m <<= 1) tmax = fmaxf(tmax, __shfl_xor(tmax, m));
      float p0 = __expf(lg0 - tmax), p1 = __expf(lg1 - tmax);
      float p2 = __expf(lg2 - tmax), p3 = __expf(lg3 - tmax);
      {
        u16* dst = pW + ((size_t)i * 12 + h) * 768 + jg0 + jj * 4;
        unsigned lo = (unsigned)f2bf(p0) | ((unsigned)f2bf(p1) << 16);
        unsigned hi = (unsigned)f2bf(p2) | ((unsigned)f2bf(p3) << 16);
        uint2 pk2; pk2.x = lo; pk2.y = hi;
        *(uint2*)dst = pk2;
      }
      float mold = mL[h];
      float mnew = fmaxf(mold, tmax);
      float st = __expf(tmax - mnew);
      float rr = __expf(mold - mnew);
      pL[(jj * 4 + 0) * 12 + h] = p0 * st;
      pL[(jj * 4 + 1) * 12 + h] = p1 * st;
      pL[(jj * 4 + 2) * 12 + h] = p2 * st;
      pL[(jj * 4 + 3) * 12 + h] = p3 * st;
      float ps = (p0 + p1 + p2 + p3) * st;
#pragma unroll
      for (int m = 1; m < 16; m <<= 1) ps += __shfl_xor(ps, m);
      if (jj == 0) {
        mTW[((size_t)i * 12 + h) * 12 + ch * 3 + tile] = tmax;
        rL[h] = rr;
        lL[h] = lL[h] * rr + ps;
        mL[h] = mnew;
      }
    }
    __syncthreads();
    // ---- E: accumulate o_pair (all 256 threads, 6 h each) ----
    {
#pragma unroll
      for (int k = 0; k < 6; k++) opacc[k] *= rL[hb6 + k];
      const int dtop = d >> 3, dlow = d & 7;
#pragma unroll 4
      for (int jj = 0; jj < 64; jj++) {
        float pv = bf2f(pS[jj * 128 + ((dtop ^ (jj & 15)) << 3) + dlow]);
        const v4f* pp = (const v4f*)&pL[jj * 12];
        v4f pm = pp[1];
        if (lohalf) {
          v4f pa = pp[0];
          opacc[0] += pa.x * pv; opacc[1] += pa.y * pv;
          opacc[2] += pa.z * pv; opacc[3] += pa.w * pv;
          opacc[4] += pm.x * pv; opacc[5] += pm.y * pv;
        } else {
          v4f pc = pp[2];
          opacc[0] += pm.z * pv; opacc[1] += pm.w * pv;
          opacc[2] += pc.x * pv; opacc[3] += pc.y * pv;
          opacc[4] += pc.z * pv; opacc[5] += pc.w * pv;
        }
      }
    }
    __syncthreads();
  }
  // ---- tail: write chunk partials ----
#pragma unroll
  for (int k = 0; k < 6; k++)
    opP[((size_t)(i * 4 + ch) * 12 + hb6 + k) * 128 + d] = opacc[k];
  if (t < 12) {
    mlP[(size_t)(i * 4 + ch) * 24 + t] = mL[t];
    mlP[(size_t)(i * 4 + ch) * 24 + 12 + t] = lL[t];
  }
}

// ---------------------------------------------------------------------------
// Combine chunk partials: o_pair -> feats[:,0:1536] (bf16); also write
// per-(i,h) global max Mg and 1/denominator iDg for the ov pass.
// ---------------------------------------------------------------------------
__global__ __launch_bounds__(256) void reduce_k(
    const float* __restrict__ opP, const float* __restrict__ mlP,
    float* __restrict__ Mg, float* __restrict__ iDg,
    u16* __restrict__ feats_bf) {
  const int i = blockIdx.x, t = threadIdx.x;
  __shared__ float wcL[4][12], invDL[12];
  if (t < 12) {
    float mc[4], lc[4];
#pragma unroll
    for (int c = 0; c < 4; c++) {
      mc[c] = mlP[(size_t)(i * 4 + c) * 24 + t];
      lc[c] = mlP[(size_t)(i * 4 + c) * 24 + 12 + t];
    }
    float M = fmaxf(fmaxf(mc[0], mc[1]), fmaxf(mc[2], mc[3]));
    float D = 0.f;
#pragma unroll
    for (int c = 0; c < 4; c++) {
      float wv = __expf(mc[c] - M);
      wcL[c][t] = wv;
      D += lc[c] * wv;
    }
    float iD = 1.f / D;
    invDL[t] = iD;
    Mg[i * 12 + t] = M;
    iDg[i * 12 + t] = iD;
  }
  __syncthreads();
  const size_t fb = (size_t)i * 2112;
#pragma unroll
  for (int s = 0; s < 6; s++) {
    int o = t + 256 * s;
    int h = o >> 7, dd = o & 127;
    float v = 0.f;
#pragma unroll
    for (int c = 0; c < 4; c++)
      v += opP[((size_t)(i * 4 + c) * 12 + h) * 128 + dd] * wcL[c][h];
    feats_bf[fb + o] = f2bf(v * invDL[h]);
  }
}

// ---------------------------------------------------------------------------
// o / og from tile-referenced p: O2[i][h][e] = sum_j attn * v2. Grid (12,12).
// attn = pW * exp(mT - Mg) * iDg, scale computed at stage time.
// ---------------------------------------------------------------------------
__global__ __launch_bounds__(256) void ov_k(
    const u16* __restrict__ pW, const float* __restrict__ mTW,
    const float* __restrict__ Mg, const float* __restrict__ iDg,
    const float* __restrict__ v2buf, float* __restrict__ O2) {
  const int i0 = blockIdx.x * 64, h = blockIdx.y, t = threadIdx.x;
  __shared__ float AL[64][65];
  __shared__ float VL[64][48];
  const int il = t & 63, eb = (t >> 6) * 12;
  v4f acc0 = {0.f, 0.f, 0.f, 0.f}, acc1 = {0.f, 0.f, 0.f, 0.f},
      acc2 = {0.f, 0.f, 0.f, 0.f};
  for (int jt = 0; jt < 12; ++jt) {
    const int j0 = jt * 64;
#pragma unroll
    for (int q = 0; q < 2; q++) {
      int idx = t + 256 * q;
      int ii = idx >> 3, c = idx & 7;
      int ig = i0 + ii;
      float sc = __expf(mTW[((size_t)ig * 12 + h) * 12 + jt] - Mg[ig * 12 + h]) *
                 iDg[ig * 12 + h];
      bf8 av = *(const bf8*)(pW + ((size_t)ig * 12 + h) * 768 + j0 + c * 8);
#pragma unroll
      for (int e = 0; e < 8; e++) AL[ii][c * 8 + e] = bf2f((u16)av[e]) * sc;
    }
#pragma unroll
    for (int q = 0; q < 3; q++) {
      int idx = t + q * 256;
      if (idx < 640) {
        int jj = idx / 10, e4 = idx % 10;
        *(v4f*)&VL[jj][e4 * 4] =
            *(const v4f*)(v2buf + (size_t)(j0 + jj) * 480 + h * 40 + e4 * 4);
      }
    }
    __syncthreads();
#pragma unroll 4
    for (int jj = 0; jj < 64; ++jj) {
      float a = AL[il][jj];
      v4f v0 = *(const v4f*)&VL[jj][eb];
      v4f v1 = *(const v4f*)&VL[jj][eb + 4];
      v4f v2 = *(const v4f*)&VL[jj][eb + 8];
      acc0 += v0 * a;
      acc1 += v1 * a;
      acc2 += v2 * a;
    }
    __syncthreads();
  }
  float* orow = O2 + ((size_t)(i0 + il) * 12 + h) * 40;
#pragma unroll
  for (int s = 0; s < 12; ++s) {
    int e = eb + s;
    if (e < 40) {
      float v = (s < 4) ? ((float*)&acc0)[s]
                        : (s < 8) ? ((float*)&acc1)[s - 4] : ((float*)&acc2)[s - 8];
      orow[e] = v;
    }
  }
}

// ---------------------------------------------------------------------------
// Finalize: local-frame transform + norms -> feats_bf[:, 1536:2112].
// ---------------------------------------------------------------------------
__global__ __launch_bounds__(256) void finalize_k(
    const float* __restrict__ O2, const float* __restrict__ fR,
    const float* __restrict__ ft, u16* __restrict__ feats_bf) {
  const int i = blockIdx.x, t = threadIdx.x;
  __shared__ float RL[9], ttL[3];
  if (t < 9) RL[t] = fR[i * 9 + t];
  if (t < 3) ttL[t] = ft[i * 3 + t];
  __syncthreads();
  const float* orow = O2 + (size_t)i * 480;
  const size_t fb = (size_t)i * 2112;
  if (t < 192) {
    int h = t >> 4, c = t & 15;
    feats_bf[fb + 1536 + h * 16 + c] = f2bf(orow[h * 40 + c]);
  }
  if (t < 96) {
    int h = t >> 3, p = t & 7;
    float og0 = orow[h * 40 + 16 + p * 3 + 0] - ttL[0];
    float og1 = orow[h * 40 + 16 + p * 3 + 1] - ttL[1];
    float og2 = orow[h * 40 + 16 + p * 3 + 2] - ttL[2];
    float o0 = RL[0] * og0 + RL[3] * og1 + RL[6] * og2;
    float o1 = RL[1] * og0 + RL[4] * og1 + RL[7] * og2;
    float o2 = RL[2] * og0 + RL[5] * og1 + RL[8] * og2;
    feats_bf[fb + 1728 + h * 24 + p * 3 + 0] = f2bf(o0);
    feats_bf[fb + 1728 + h * 24 + p * 3 + 1] = f2bf(o1);
    feats_bf[fb + 1728 + h * 24 + p * 3 + 2] = f2bf(o2);
    feats_bf[fb + 2016 + h * 8 + p] = f2bf(sqrtf(o0 * o0 + o1 * o1 + o2 * o2 + 1e-8f));
  }
}

// ---------------------------------------------------------------------------
extern "C" void kernel_launch(void* const* d_in, const int* in_sizes, int n_in,
                              void* d_out, int out_size, void* d_ws, size_t ws_size,
                              hipStream_t stream) {
  const float* single = (const float*)d_in[0];
  const float* pair = (const float*)d_in[1];
  const float* fR = (const float*)d_in[2];
  const float* ft = (const float*)d_in[3];
  const float* W_qkv = (const float*)d_in[4];
  const float* W_b = (const float*)d_in[5];
  const float* W_qkp = (const float*)d_in[6];
  const float* W_vp = (const float*)d_in[7];
  const float* gamma = (const float*)d_in[8];
  const float* W_out = (const float*)d_in[9];
  const float* b_out = (const float*)d_in[10];
  float* out = (float*)d_out;

  float* ws = (float*)d_ws;
  float* projQKV = ws;                      // 442368
  float* projQKP = ws + 442368;             // 221184
  float* projVP  = ws + 663552;             // 221184
  float* qbuf    = ws + 884736;             // 147456
  float* kbuf    = ws + 1032192;            // 147456
  float* v2buf   = ws + 1179648;            // 368640
  float* qgbuf   = ws + 1548288;            // 110592
  float* kgbuf   = ws + 1658880;            // 110592
  float* sqbuf   = ws + 1769472;            // 9216
  float* skbuf   = ws + 1778688;            // 9216
  float* opP     = ws + 1787904;            // 4718592
  float* mlP     = ws + 6506496;            // 73728
  float* mTW     = ws + 6580224;            // 110592
  float* Mg      = ws + 6690816;            // 9216
  float* iDg     = ws + 6700032;            // 9216
  float* O2      = ws + 6709248;            // 368640
  u16* ub        = (u16*)(ws + 7077888);
  u16* single_bf = ub;                      // 294912
  u16* WqkvFrag  = ub + 294912;             // 221184
  u16* WbFrag    = ub + 516096;             // 2048
  u16* WoutFrag  = ub + 518144;             // 811008
  u16* pW        = ub + 1329152;            // 7077888
  u16* feats_bf  = ub + 8407040;            // 1622016

  convert_bf<<<144, 256, 0, stream>>>(single, single_bf, 36864);
  wfrag_k<<<12, 256, 0, stream>>>(W_qkv, WqkvFrag, 384, 576, 1.f);
  wfrag_k<<<4, 256, 0, stream>>>(W_b, WbFrag, 128, 12, W_L_);
  wfrag_k<<<66, 256, 0, stream>>>(W_out, WoutFrag, 2112, 384, 1.f);
  gemm_f32<<<dim3(9, 12), 256, 0, stream>>>(single, W_qkp, projQKP, 768, 288, 384);
  gemm_f32<<<dim3(9, 12), 256, 0, stream>>>(single, W_vp, projVP, 768, 288, 384);
  mfma_gemm<<<dim3(18, 12), 256, 0, stream>>>(single_bf, WqkvFrag, nullptr,
                                              projQKV, 768, 576, 384, 576);
  prep_kernel<<<768, 256, 0, stream>>>(projQKV, projQKP, projVP, fR, ft,
                                       qbuf, kbuf, v2buf, qgbuf, kgbuf, sqbuf, skbuf);
  ipa_fused<<<dim3(4, 768), 256, 0, stream>>>(pair, WbFrag, gamma, qbuf, kbuf,
                                              qgbuf, kgbuf, sqbuf, skbuf,
                                              pW, mTW, opP, mlP);
  reduce_k<<<768, 256, 0, stream>>>(opP, mlP, Mg, iDg, feats_bf);
  ov_k<<<dim3(12, 12), 256, 0, stream>>>(pW, mTW, Mg, iDg, v2buf, O2);
  finalize_k<<<768, 256, 0, stream>>>(O2, fR, ft, feats_bf);
  mfma_gemm<<<dim3(12, 12), 256, 0, stream>>>(feats_bf, WoutFrag, b_out,
                                              out, 768, 384, 2112, 384);
}

// Round 6
// 353.043 us; speedup vs baseline: 1.1084x; 1.1084x over previous
//
#include <hip/hip_runtime.h>
#include <hip/hip_bf16.h>

typedef float v4f __attribute__((ext_vector_type(4)));
typedef short bf8 __attribute__((ext_vector_type(8)));  // 8 bf16 in 4 VGPRs
typedef unsigned short u16;

constexpr float W_C_ = 0.23570226039551584f;  // sqrt(2/(9*4))
constexpr float W_L_ = 0.5773502691896258f;   // sqrt(1/3)

__device__ __forceinline__ u16 f2bf(float f) {  // RNE f32->bf16
  unsigned u = __float_as_uint(f);
  return (u16)((u + 0x7FFFu + ((u >> 16) & 1u)) >> 16);
}
__device__ __forceinline__ float bf2f(u16 h) {
  return __uint_as_float(((unsigned)h) << 16);
}
__device__ __forceinline__ float dot4(v4f a, v4f b) {
  return a.x * b.x + a.y * b.y + a.z * b.z + a.w * b.w;
}

// ---------------------------------------------------------------------------
// f32 -> bf16 elementwise (n8 = n/8 chunks)
// ---------------------------------------------------------------------------
__global__ __launch_bounds__(256) void convert_bf(const float* __restrict__ src,
                                                  u16* __restrict__ dst, int n8) {
  int idx = blockIdx.x * 256 + threadIdx.x;
  if (idx < n8) {
    v4f a = ((const v4f*)src)[idx * 2];
    v4f b = ((const v4f*)src)[idx * 2 + 1];
    bf8 o;
    o[0] = (short)f2bf(a.x); o[1] = (short)f2bf(a.y);
    o[2] = (short)f2bf(a.z); o[3] = (short)f2bf(a.w);
    o[4] = (short)f2bf(b.x); o[5] = (short)f2bf(b.y);
    o[6] = (short)f2bf(b.z); o[7] = (short)f2bf(b.w);
    ((bf8*)dst)[idx] = o;
  }
}

// ---------------------------------------------------------------------------
// Pre-fragment W[K][N] (f32, optional scale) into MFMA B-fragment order:
// frag[ks][nt][lane][e] (bf16), B[k=ks*32+(l>>4)*8+e][col=nt*16+(l&15)].
// ---------------------------------------------------------------------------
__global__ __launch_bounds__(256) void wfrag_k(const float* __restrict__ W,
                                               u16* __restrict__ frag,
                                               int K, int N, float scale) {
  __shared__ float Ws[32 * 384];
  const int ks = blockIdx.x, k0 = ks * 32, t = threadIdx.x;
  const int NTfull = (N + 15) >> 4;
  for (int n0 = 0; n0 < N; n0 += 384) {
    int PN = N - n0; if (PN > 384) PN = 384;
    __syncthreads();
    for (int idx = t; idx < 32 * PN; idx += 256) {
      int r = idx / PN, c = idx - r * PN;
      Ws[r * PN + c] = W[(size_t)(k0 + r) * N + n0 + c];
    }
    __syncthreads();
    int NTp = (PN + 15) >> 4;
    for (int c = t; c < NTp * 64; c += 256) {
      int nt = c >> 6, l = c & 63;
      int col = nt * 16 + (l & 15);
      bf8 o;
#pragma unroll
      for (int e = 0; e < 8; e++) {
        int rr = (l >> 4) * 8 + e;
        float f = (col < PN) ? Ws[rr * PN + col] * scale : 0.f;
        o[e] = (short)f2bf(f);
      }
      ((bf8*)frag)[((size_t)ks * NTfull + (n0 >> 4) + nt) * 64 + l] = o;
    }
  }
}

// ---------------------------------------------------------------------------
// bf16 MFMA GEMM (pre-fragmented B direct from global), BM=64 BN=32.
// ---------------------------------------------------------------------------
__global__ __launch_bounds__(256) void mfma_gemm(
    const u16* __restrict__ Abf, const u16* __restrict__ Bfrag,
    const float* __restrict__ bias, float* __restrict__ C,
    int M, int N, int K, int ldc) {
  __shared__ u16 As[64 * 32];
  const int t = threadIdx.x, w = t >> 6, l = t & 63;
  const int bi = blockIdx.y * 64, nt0 = blockIdx.x * 2;
  const int NT = N >> 4, KS = K >> 5;
  v4f acc0 = {0.f, 0.f, 0.f, 0.f}, acc1 = {0.f, 0.f, 0.f, 0.f};
  const int srow = t >> 2, sc = t & 3;
  const int wslot = (sc ^ (srow & 3)) * 8;
  const bf8* Bf = (const bf8*)Bfrag;

  bf8 areg = *(const bf8*)(Abf + (size_t)(bi + srow) * K + sc * 8);
  bf8 b0 = Bf[(size_t)(0 * NT + nt0) * 64 + l];
  bf8 b1 = Bf[(size_t)(0 * NT + nt0 + 1) * 64 + l];
  const int rdoff = (w * 16 + (l & 15)) * 32 + (((l >> 4) ^ (l & 3)) * 8);
  for (int ks = 0; ks < KS; ks++) {
    *(bf8*)&As[srow * 32 + wslot] = areg;
    bf8 an, bn0, bn1;
    if (ks + 1 < KS) {
      an = *(const bf8*)(Abf + (size_t)(bi + srow) * K + (ks + 1) * 32 + sc * 8);
      bn0 = Bf[(size_t)((ks + 1) * NT + nt0) * 64 + l];
      bn1 = Bf[(size_t)((ks + 1) * NT + nt0 + 1) * 64 + l];
    }
    __syncthreads();
    bf8 af = *(const bf8*)&As[rdoff];
    acc0 = __builtin_amdgcn_mfma_f32_16x16x32_bf16(af, b0, acc0, 0, 0, 0);
    acc1 = __builtin_amdgcn_mfma_f32_16x16x32_bf16(af, b1, acc1, 0, 0, 0);
    __syncthreads();
    areg = an; b0 = bn0; b1 = bn1;
  }
  int col0 = nt0 * 16 + (l & 15), col1 = col0 + 16;
  float bb0 = bias ? bias[col0] : 0.f;
  float bb1 = bias ? bias[col1] : 0.f;
#pragma unroll
  for (int r = 0; r < 4; r++) {
    int row = bi + w * 16 + (l >> 4) * 4 + r;
    C[(size_t)row * ldc + col0] = acc0[r] + bb0;
    C[(size_t)row * ldc + col1] = acc1[r] + bb1;
  }
}

// ---------------------------------------------------------------------------
// Prep: reshape projections, apply frames, build per-residue buffers.
// qbuf/kbuf [n][h*16+c]; v2buf [n][h*40+e]; qgbuf/kgbuf [n][h*12+e];
// sqbuf/skbuf [n][12].
// ---------------------------------------------------------------------------
__global__ __launch_bounds__(256) void prep_kernel(
    const float* __restrict__ projQKV, const float* __restrict__ projQKP,
    const float* __restrict__ projVP, const float* __restrict__ fR,
    const float* __restrict__ ft,
    float* __restrict__ qbuf, float* __restrict__ kbuf, float* __restrict__ v2buf,
    float* __restrict__ qgbuf, float* __restrict__ kgbuf,
    float* __restrict__ sqbuf, float* __restrict__ skbuf) {
  const int n = blockIdx.x, t = threadIdx.x;
  __shared__ float R[9], tt[3];
  __shared__ float qgL[144], kgL[144];
  if (t < 9) R[t] = fR[n * 9 + t];
  if (t < 3) tt[t] = ft[n * 3 + t];
  __syncthreads();
  const float* rQKV = projQKV + (size_t)n * 576;
  const float* rQKP = projQKP + (size_t)n * 288;
  const float* rVP = projVP + (size_t)n * 288;
  if (t < 192) {
    int h = t >> 4, c = t & 15;
    qbuf[(size_t)n * 192 + t] = rQKV[c * 12 + h];
    kbuf[(size_t)n * 192 + t] = rQKV[192 + c * 12 + h];
    v2buf[(size_t)n * 480 + h * 40 + c] = rQKV[384 + c * 12 + h];
  }
  if (t < 144) {
    int e = t / 12, h = t % 12;
    int p = e / 3, x = e % 3;
    float aq = tt[x], ak = tt[x];
#pragma unroll
    for (int y = 0; y < 3; y++) {
      float r = R[x * 3 + y];
      aq += r * rQKP[p * 36 + y * 12 + h];
      ak += r * rQKP[144 + p * 36 + y * 12 + h];
    }
    qgL[h * 12 + e] = aq;
    kgL[h * 12 + e] = ak;
    qgbuf[(size_t)n * 144 + h * 12 + e] = aq;
    kgbuf[(size_t)n * 144 + h * 12 + e] = ak;
  }
  for (int idx = t; idx < 288; idx += 256) {
    int e = idx / 12, h = idx % 12;
    int p = e / 3, x = e % 3;
    float a = tt[x];
#pragma unroll
    for (int y = 0; y < 3; y++) a += R[x * 3 + y] * rVP[p * 36 + y * 12 + h];
    v2buf[(size_t)n * 480 + h * 40 + 16 + e] = a;
  }
  __syncthreads();
  if (t < 12) {
    float s = 0.f;
#pragma unroll
    for (int e = 0; e < 12; e++) { float v = qgL[t * 12 + e]; s += v * v; }
    sqbuf[n * 12 + t] = s;
  } else if (t < 24) {
    int h = t - 12;
    float s = 0.f;
#pragma unroll
    for (int e = 0; e < 12; e++) { float v = kgL[h * 12 + e]; s += v * v; }
    skbuf[n * 12 + h] = s;
  }
}

// ---------------------------------------------------------------------------
// Pair pass 1: bias MFMA + full logits (f32) + bf16 pair copy.
// Grid (12 jt, 768 i); one 64-j tile per block, 3 barriers total.
// ---------------------------------------------------------------------------
__global__ __launch_bounds__(256) void biaslogit_k(
    const float* __restrict__ pair, const u16* __restrict__ WbFrag,
    const float* __restrict__ gamma,
    const float* __restrict__ qbuf, const float* __restrict__ kbuf,
    const float* __restrict__ qgbuf, const float* __restrict__ kgbuf,
    const float* __restrict__ sqbuf, const float* __restrict__ skbuf,
    u16* __restrict__ pair_bf, float* __restrict__ logits) {
  const int jt = blockIdx.x, i = blockIdx.y;
  const int t = threadIdx.x, w = t >> 6, l = t & 63;
  __shared__ u16 pS[64 * 128];
  __shared__ float lgL[64 * 15];
  __shared__ float qL[192], qgL[144], c1L[12], c2L[12];

  if (t < 192) qL[t] = qbuf[(size_t)i * 192 + t];
  if (t < 144) qgL[t] = qgbuf[(size_t)i * 144 + t];
  if (t < 12) {
    float g = gamma[t];
    float hw = fmaxf(g, 0.f) + log1pf(expf(-fabsf(g)));
    c1L[t] = W_L_ * W_C_ * hw;
    c2L[t] = -0.5f * c1L[t] * sqbuf[i * 12 + t];
  }
  bf8 wb[4];
  const bf8* Wf = (const bf8*)WbFrag;
#pragma unroll
  for (int ks = 0; ks < 4; ks++) wb[ks] = Wf[ks * 64 + l];

  // stage pair tile -> swizzled bf16 LDS + bf16 global copy
  const float* pg = pair + ((size_t)i * 768 + jt * 64) * 128;
  u16* pbg = pair_bf + ((size_t)i * 768 + jt * 64) * 128;
#pragma unroll
  for (int it = 0; it < 4; it++) {
    int idx = t + 256 * it;
    int j = idx >> 4, c = idx & 15;
    v4f x0 = *(const v4f*)(pg + j * 128 + c * 8);
    v4f x1 = *(const v4f*)(pg + j * 128 + c * 8 + 4);
    bf8 pk;
    pk[0] = (short)f2bf(x0.x); pk[1] = (short)f2bf(x0.y);
    pk[2] = (short)f2bf(x0.z); pk[3] = (short)f2bf(x0.w);
    pk[4] = (short)f2bf(x1.x); pk[5] = (short)f2bf(x1.y);
    pk[6] = (short)f2bf(x1.z); pk[7] = (short)f2bf(x1.w);
    *(bf8*)&pS[j * 128 + ((c ^ (j & 15)) * 8)] = pk;
    *(bf8*)(pbg + j * 128 + c * 8) = pk;
  }
  __syncthreads();

  // MFMA: W_L * (pair @ W_b) -> lgL[j][h]
  {
    v4f acc = {0.f, 0.f, 0.f, 0.f};
#pragma unroll
    for (int ks = 0; ks < 4; ks++) {
      int slot = (ks * 4 + (l >> 4)) ^ (l & 15);
      bf8 af = *(const bf8*)&pS[(w * 16 + (l & 15)) * 128 + slot * 8];
      acc = __builtin_amdgcn_mfma_f32_16x16x32_bf16(af, wb[ks], acc, 0, 0, 0);
    }
    int h = l & 15;
    if (h < 12) {
#pragma unroll
      for (int r = 0; r < 4; r++)
        lgL[(w * 16 + (l >> 4) * 4 + r) * 15 + h] = acc[r];
    }
  }
  __syncthreads();

  // qk + point-dist terms in f32 (k-side from L2)
  {
    const int j = t >> 2, hg = t & 3;
    const int jg = jt * 64 + j;
#pragma unroll
    for (int hh = 0; hh < 3; hh++) {
      int h = hg * 3 + hh;
      const v4f* kk = (const v4f*)(kbuf + (size_t)jg * 192 + h * 16);
      const v4f* qq = (const v4f*)&qL[h * 16];
      float qk = dot4(kk[0], qq[0]) + dot4(kk[1], qq[1]) +
                 dot4(kk[2], qq[2]) + dot4(kk[3], qq[3]);
      const v4f* kg = (const v4f*)(kgbuf + (size_t)jg * 144 + h * 12);
      const v4f* qg = (const v4f*)&qgL[h * 12];
      float cr = dot4(kg[0], qg[0]) + dot4(kg[1], qg[1]) + dot4(kg[2], qg[2]);
      float sk = skbuf[(size_t)jg * 12 + h];
      lgL[j * 15 + h] += 0.25f * W_L_ * qk + c1L[h] * (cr - 0.5f * sk) + c2L[h];
    }
  }
  __syncthreads();

  // write logits [i][h][jt*64+j], coalesced in j
#pragma unroll
  for (int s = 0; s < 3; s++) {
    int o = t + 256 * s;
    int h = o >> 6, j = o & 63;
    logits[((size_t)i * 12 + h) * 768 + jt * 64 + j] = lgL[j * 15 + h];
  }
}

// ---------------------------------------------------------------------------
// Softmax over j: one wave per (i,h) row of 768 f32 -> bf16 attn. Grid 2304.
// ---------------------------------------------------------------------------
__global__ __launch_bounds__(256) void softmax_bf(const float* __restrict__ L,
                                                  u16* __restrict__ attn) {
  const int row = blockIdx.x * 4 + (threadIdx.x >> 6);
  const int lane = threadIdx.x & 63;
  const v4f* p = (const v4f*)(L + (size_t)row * 768);
  v4f a0 = p[lane], a1 = p[lane + 64], a2 = p[lane + 128];
  float m0 = fmaxf(fmaxf(a0.x, a0.y), fmaxf(a0.z, a0.w));
  float m1 = fmaxf(fmaxf(a1.x, a1.y), fmaxf(a1.z, a1.w));
  float m2 = fmaxf(fmaxf(a2.x, a2.y), fmaxf(a2.z, a2.w));
  float m = fmaxf(m0, fmaxf(m1, m2));
#pragma unroll
  for (int s = 32; s >= 1; s >>= 1) m = fmaxf(m, __shfl_xor(m, s));
  a0.x = __expf(a0.x - m); a0.y = __expf(a0.y - m);
  a0.z = __expf(a0.z - m); a0.w = __expf(a0.w - m);
  a1.x = __expf(a1.x - m); a1.y = __expf(a1.y - m);
  a1.z = __expf(a1.z - m); a1.w = __expf(a1.w - m);
  a2.x = __expf(a2.x - m); a2.y = __expf(a2.y - m);
  a2.z = __expf(a2.z - m); a2.w = __expf(a2.w - m);
  float s = a0.x + a0.y + a0.z + a0.w + a1.x + a1.y + a1.z + a1.w +
            a2.x + a2.y + a2.z + a2.w;
#pragma unroll
  for (int q = 32; q >= 1; q >>= 1) s += __shfl_xor(s, q);
  float inv = 1.f / s;
  a0 *= inv; a1 *= inv; a2 *= inv;
  u16* arow = attn + (size_t)row * 768;
  uint2 pk;
  pk.x = (unsigned)f2bf(a0.x) | ((unsigned)f2bf(a0.y) << 16);
  pk.y = (unsigned)f2bf(a0.z) | ((unsigned)f2bf(a0.w) << 16);
  *(uint2*)&arow[lane * 4] = pk;
  pk.x = (unsigned)f2bf(a1.x) | ((unsigned)f2bf(a1.y) << 16);
  pk.y = (unsigned)f2bf(a1.z) | ((unsigned)f2bf(a1.w) << 16);
  *(uint2*)&arow[256 + lane * 4] = pk;
  pk.x = (unsigned)f2bf(a2.x) | ((unsigned)f2bf(a2.y) << 16);
  pk.y = (unsigned)f2bf(a2.z) | ((unsigned)f2bf(a2.w) << 16);
  *(uint2*)&arow[512 + lane * 4] = pk;
}

// ---------------------------------------------------------------------------
// Pair pass 2 (bf16, likely L3-resident): o_pair -> feats[:,0:1536].
// Block per i; wave w covers jj=w*16..+15; lane owns 4d x 6h accumulators;
// cross-wave LDS reduction at the end. attn already normalized.
// ---------------------------------------------------------------------------
__global__ __launch_bounds__(256) void opair_k(
    const u16* __restrict__ pair_bf, const u16* __restrict__ attn,
    u16* __restrict__ feats_bf) {
  const int i = blockIdx.x, t = threadIdx.x;
  const int w = t >> 6, l = t & 63;
  const int dq = l & 31, hh = l >> 5;
  __shared__ float smemf[6160];          // 24.6 KB, overlaid regions
  u16* pS = (u16*)smemf;                 // [64*128] bf16 swizzled (16 KB)
  float* ALf = smemf + 4096;             // [12][68]
  float* red = smemf;                    // reduction overlay (6144 f)

  v4f acc[6];
#pragma unroll
  for (int k = 0; k < 6; k++) acc[k] = (v4f){0.f, 0.f, 0.f, 0.f};

  bf8 pr[4];
  bf8 areg;
  {
    const u16* pg = pair_bf + (size_t)i * 768 * 128;
#pragma unroll
    for (int it = 0; it < 4; it++) {
      int idx = t + 256 * it;
      pr[it] = *(const bf8*)(pg + (idx >> 4) * 128 + (idx & 15) * 8);
    }
    if (t < 96)
      areg = *(const bf8*)(attn + ((size_t)i * 12 + (t >> 3)) * 768 + (t & 7) * 8);
  }
  for (int jt = 0; jt < 12; jt++) {
#pragma unroll
    for (int it = 0; it < 4; it++) {
      int idx = t + 256 * it;
      int j = idx >> 4, c = idx & 15;
      *(bf8*)&pS[j * 128 + ((c ^ (j & 15)) * 8)] = pr[it];
    }
    if (t < 96) {
      int hA = t >> 3, c = t & 7;
#pragma unroll
      for (int e = 0; e < 8; e++) ALf[hA * 68 + c * 8 + e] = bf2f((u16)areg[e]);
    }
    if (jt < 11) {
      const u16* pg = pair_bf + ((size_t)i * 768 + (jt + 1) * 64) * 128;
#pragma unroll
      for (int it = 0; it < 4; it++) {
        int idx = t + 256 * it;
        pr[it] = *(const bf8*)(pg + (idx >> 4) * 128 + (idx & 15) * 8);
      }
      if (t < 96)
        areg = *(const bf8*)(attn + ((size_t)i * 12 + (t >> 3)) * 768 +
                             (jt + 1) * 64 + (t & 7) * 8);
    }
    __syncthreads();
#pragma unroll
    for (int jj16 = 0; jj16 < 16; jj16++) {
      int jj = w * 16 + jj16;
      const u16* pv4 = &pS[jj * 128 + (((dq >> 1) ^ (jj & 15)) * 8) + (dq & 1) * 4];
      v4f pv;
      pv.x = bf2f(pv4[0]); pv.y = bf2f(pv4[1]);
      pv.z = bf2f(pv4[2]); pv.w = bf2f(pv4[3]);
      float a0 = ALf[(hh * 6 + 0) * 68 + jj];
      float a1 = ALf[(hh * 6 + 1) * 68 + jj];
      float a2 = ALf[(hh * 6 + 2) * 68 + jj];
      float a3 = ALf[(hh * 6 + 3) * 68 + jj];
      float a4 = ALf[(hh * 6 + 4) * 68 + jj];
      float a5 = ALf[(hh * 6 + 5) * 68 + jj];
      acc[0] += pv * a0; acc[1] += pv * a1; acc[2] += pv * a2;
      acc[3] += pv * a3; acc[4] += pv * a4; acc[5] += pv * a5;
    }
    __syncthreads();
  }
  // cross-wave reduction
#pragma unroll
  for (int k = 0; k < 6; k++)
    *(v4f*)&red[(w * 12 + hh * 6 + k) * 128 + dq * 4] = acc[k];
  __syncthreads();
  const size_t fb = (size_t)i * 2112;
#pragma unroll
  for (int s = 0; s < 6; s++) {
    int o = t + 256 * s;
    int ho = o >> 7, dd = o & 127;
    float v = red[ho * 128 + dd] + red[(12 + ho) * 128 + dd] +
              red[(24 + ho) * 128 + dd] + red[(36 + ho) * 128 + dd];
    feats_bf[fb + o] = f2bf(v);
  }
}

// ---------------------------------------------------------------------------
// o / og: O2[i][h][e] = sum_j attn[i,h,j]*v2[j,h,e]. Grid (12 i-tiles, 12 h).
// ---------------------------------------------------------------------------
__global__ __launch_bounds__(256) void ov_k(
    const u16* __restrict__ attn, const float* __restrict__ v2buf,
    float* __restrict__ O2) {
  const int i0 = blockIdx.x * 64, h = blockIdx.y, t = threadIdx.x;
  __shared__ float AL[64][65];
  __shared__ float VL[64][48];
  const int il = t & 63, eb = (t >> 6) * 12;
  v4f acc0 = {0.f, 0.f, 0.f, 0.f}, acc1 = {0.f, 0.f, 0.f, 0.f},
      acc2 = {0.f, 0.f, 0.f, 0.f};
  for (int jt = 0; jt < 12; ++jt) {
    const int j0 = jt * 64;
#pragma unroll
    for (int q = 0; q < 2; q++) {
      int idx = t + 256 * q;
      int ii = idx >> 3, c = idx & 7;
      bf8 av = *(const bf8*)(attn + ((size_t)(i0 + ii) * 12 + h) * 768 + j0 + c * 8);
#pragma unroll
      for (int e = 0; e < 8; e++) AL[ii][c * 8 + e] = bf2f((u16)av[e]);
    }
#pragma unroll
    for (int q = 0; q < 3; q++) {
      int idx = t + q * 256;
      if (idx < 640) {
        int jj = idx / 10, e4 = idx % 10;
        *(v4f*)&VL[jj][e4 * 4] =
            *(const v4f*)(v2buf + (size_t)(j0 + jj) * 480 + h * 40 + e4 * 4);
      }
    }
    __syncthreads();
#pragma unroll 4
    for (int jj = 0; jj < 64; ++jj) {
      float a = AL[il][jj];
      v4f v0 = *(const v4f*)&VL[jj][eb];
      v4f v1 = *(const v4f*)&VL[jj][eb + 4];
      v4f v2 = *(const v4f*)&VL[jj][eb + 8];
      acc0 += v0 * a;
      acc1 += v1 * a;
      acc2 += v2 * a;
    }
    __syncthreads();
  }
  float* orow = O2 + ((size_t)(i0 + il) * 12 + h) * 40;
#pragma unroll
  for (int s = 0; s < 12; ++s) {
    int e = eb + s;
    if (e < 40) {
      float v = (s < 4) ? ((float*)&acc0)[s]
                        : (s < 8) ? ((float*)&acc1)[s - 4] : ((float*)&acc2)[s - 8];
      orow[e] = v;
    }
  }
}

// ---------------------------------------------------------------------------
// Finalize: local-frame transform + norms -> feats_bf[:, 1536:2112].
// ---------------------------------------------------------------------------
__global__ __launch_bounds__(256) void finalize_k(
    const float* __restrict__ O2, const float* __restrict__ fR,
    const float* __restrict__ ft, u16* __restrict__ feats_bf) {
  const int i = blockIdx.x, t = threadIdx.x;
  __shared__ float RL[9], ttL[3];
  if (t < 9) RL[t] = fR[i * 9 + t];
  if (t < 3) ttL[t] = ft[i * 3 + t];
  __syncthreads();
  const float* orow = O2 + (size_t)i * 480;
  const size_t fb = (size_t)i * 2112;
  if (t < 192) {
    int h = t >> 4, c = t & 15;
    feats_bf[fb + 1536 + h * 16 + c] = f2bf(orow[h * 40 + c]);
  }
  if (t < 96) {
    int h = t >> 3, p = t & 7;
    float og0 = orow[h * 40 + 16 + p * 3 + 0] - ttL[0];
    float og1 = orow[h * 40 + 16 + p * 3 + 1] - ttL[1];
    float og2 = orow[h * 40 + 16 + p * 3 + 2] - ttL[2];
    float o0 = RL[0] * og0 + RL[3] * og1 + RL[6] * og2;
    float o1 = RL[1] * og0 + RL[4] * og1 + RL[7] * og2;
    float o2 = RL[2] * og0 + RL[5] * og1 + RL[8] * og2;
    feats_bf[fb + 1728 + h * 24 + p * 3 + 0] = f2bf(o0);
    feats_bf[fb + 1728 + h * 24 + p * 3 + 1] = f2bf(o1);
    feats_bf[fb + 1728 + h * 24 + p * 3 + 2] = f2bf(o2);
    feats_bf[fb + 2016 + h * 8 + p] = f2bf(sqrtf(o0 * o0 + o1 * o1 + o2 * o2 + 1e-8f));
  }
}

// ---------------------------------------------------------------------------
extern "C" void kernel_launch(void* const* d_in, const int* in_sizes, int n_in,
                              void* d_out, int out_size, void* d_ws, size_t ws_size,
                              hipStream_t stream) {
  const float* single = (const float*)d_in[0];
  const float* pair = (const float*)d_in[1];
  const float* fR = (const float*)d_in[2];
  const float* ft = (const float*)d_in[3];
  const float* W_qkv = (const float*)d_in[4];
  const float* W_b = (const float*)d_in[5];
  const float* W_qkp = (const float*)d_in[6];
  const float* W_vp = (const float*)d_in[7];
  const float* gamma = (const float*)d_in[8];
  const float* W_out = (const float*)d_in[9];
  const float* b_out = (const float*)d_in[10];
  float* out = (float*)d_out;

  float* ws = (float*)d_ws;
  float* projQKV = ws;                      // 442368
  float* projQKP = ws + 442368;             // 221184
  float* projVP  = ws + 663552;             // 221184
  float* qbuf    = ws + 884736;             // 147456
  float* kbuf    = ws + 1032192;            // 147456
  float* v2buf   = ws + 1179648;            // 368640
  float* qgbuf   = ws + 1548288;            // 110592
  float* kgbuf   = ws + 1658880;            // 110592
  float* sqbuf   = ws + 1769472;            // 9216
  float* skbuf   = ws + 1778688;            // 9216
  float* logits  = ws + 1787904;            // 7077888
  float* O2      = ws + 8865792;            // 368640
  u16* ub        = (u16*)(ws + 9234432);
  u16* single_bf = ub;                      // 294912
  u16* WqkvFrag  = ub + 294912;             // 221184
  u16* WqkpFrag  = ub + 516096;             // 110592
  u16* WvpFrag   = ub + 626688;             // 110592
  u16* WbFrag    = ub + 737280;             // 2048
  u16* WoutFrag  = ub + 739328;             // 811008
  u16* attn      = ub + 1550336;            // 7077888
  u16* feats_bf  = ub + 8628224;            // 1622016
  u16* pair_bf   = ub + 10250240;           // 75497472

  // conversions + weight fragmenting
  convert_bf<<<144, 256, 0, stream>>>(single, single_bf, 36864);
  wfrag_k<<<12, 256, 0, stream>>>(W_qkv, WqkvFrag, 384, 576, 1.f);
  wfrag_k<<<12, 256, 0, stream>>>(W_qkp, WqkpFrag, 384, 288, 1.f);
  wfrag_k<<<12, 256, 0, stream>>>(W_vp, WvpFrag, 384, 288, 1.f);
  wfrag_k<<<4, 256, 0, stream>>>(W_b, WbFrag, 128, 12, W_L_);
  wfrag_k<<<66, 256, 0, stream>>>(W_out, WoutFrag, 2112, 384, 1.f);
  // projections (all bf16 MFMA)
  mfma_gemm<<<dim3(18, 12), 256, 0, stream>>>(single_bf, WqkvFrag, nullptr,
                                              projQKV, 768, 576, 384, 576);
  mfma_gemm<<<dim3(9, 12), 256, 0, stream>>>(single_bf, WqkpFrag, nullptr,
                                             projQKP, 768, 288, 384, 288);
  mfma_gemm<<<dim3(9, 12), 256, 0, stream>>>(single_bf, WvpFrag, nullptr,
                                             projVP, 768, 288, 384, 288);
  // reshape + frames
  prep_kernel<<<768, 256, 0, stream>>>(projQKV, projQKP, projVP, fR, ft,
                                       qbuf, kbuf, v2buf, qgbuf, kgbuf, sqbuf, skbuf);
  // pair pass 1: bias MFMA + logits + bf16 pair copy
  biaslogit_k<<<dim3(12, 768), 256, 0, stream>>>(pair, WbFrag, gamma, qbuf, kbuf,
                                                 qgbuf, kgbuf, sqbuf, skbuf,
                                                 pair_bf, logits);
  // softmax -> attn bf16
  softmax_bf<<<2304, 256, 0, stream>>>(logits, attn);
  // pair pass 2: o_pair
  opair_k<<<768, 256, 0, stream>>>(pair_bf, attn, feats_bf);
  // o / og
  ov_k<<<dim3(12, 12), 256, 0, stream>>>(attn, v2buf, O2);
  // local frames + norms
  finalize_k<<<768, 256, 0, stream>>>(O2, fR, ft, feats_bf);
  // output projection (bf16 MFMA)
  mfma_gemm<<<dim3(12, 12), 256, 0, stream>>>(feats_bf, WoutFrag, b_out,
                                              out, 768, 384, 2112, 384);
}

// Round 7
// 296.890 us; speedup vs baseline: 1.3180x; 1.1891x over previous
//
#include <hip/hip_runtime.h>
#include <hip/hip_bf16.h>

typedef float v4f __attribute__((ext_vector_type(4)));
typedef short bf8 __attribute__((ext_vector_type(8)));  // 8 bf16 in 4 VGPRs
typedef unsigned short u16;

constexpr float W_C_ = 0.23570226039551584f;  // sqrt(2/(9*4))
constexpr float W_L_ = 0.5773502691896258f;   // sqrt(1/3)

__device__ __forceinline__ u16 f2bf(float f) {  // RNE f32->bf16
  unsigned u = __float_as_uint(f);
  return (u16)((u + 0x7FFFu + ((u >> 16) & 1u)) >> 16);
}
__device__ __forceinline__ float bf2f(u16 h) {
  return __uint_as_float(((unsigned)h) << 16);
}
__device__ __forceinline__ float dot4(v4f a, v4f b) {
  return a.x * b.x + a.y * b.y + a.z * b.z + a.w * b.w;
}

// ---------------------------------------------------------------------------
// Fused weight prep: blocks [0,144) convert single->bf16; the rest fragment
// W_qkv/W_qkp/W_vp (into one combined frag, N=1152), W_b, W_out.
// ---------------------------------------------------------------------------
__device__ void wfrag_dev(const float* __restrict__ W, u16* __restrict__ frag,
                          int K, int N, float scale, int ks, int ntBase,
                          int NTtotal, float* Ws, int t) {
  const int k0 = ks * 32;
  for (int n0 = 0; n0 < N; n0 += 384) {
    int PN = N - n0; if (PN > 384) PN = 384;
    __syncthreads();
    for (int idx = t; idx < 32 * PN; idx += 256) {
      int r = idx / PN, c = idx - r * PN;
      Ws[r * PN + c] = W[(size_t)(k0 + r) * N + n0 + c];
    }
    __syncthreads();
    int NTp = (PN + 15) >> 4;
    for (int c = t; c < NTp * 64; c += 256) {
      int nt = c >> 6, l = c & 63;
      int col = nt * 16 + (l & 15);
      bf8 o;
#pragma unroll
      for (int e = 0; e < 8; e++) {
        int rr = (l >> 4) * 8 + e;
        float f = (col < PN) ? Ws[rr * PN + col] * scale : 0.f;
        o[e] = (short)f2bf(f);
      }
      ((bf8*)frag)[((size_t)ks * NTtotal + ntBase + (n0 >> 4) + nt) * 64 + l] = o;
    }
  }
}

__global__ __launch_bounds__(256) void wfrag_all(
    const float* __restrict__ single, u16* __restrict__ single_bf,
    const float* __restrict__ W_qkv, const float* __restrict__ W_qkp,
    const float* __restrict__ W_vp, const float* __restrict__ W_b,
    const float* __restrict__ W_out,
    u16* __restrict__ WallFrag, u16* __restrict__ WbFrag,
    u16* __restrict__ WoutFrag) {
  __shared__ float Ws[32 * 384];
  const int b = blockIdx.x, t = threadIdx.x;
  if (b < 144) {  // convert single (294912 f32) to bf16, 8 per thread
    int idx = b * 256 + t;
    v4f a = ((const v4f*)single)[idx * 2];
    v4f c = ((const v4f*)single)[idx * 2 + 1];
    bf8 o;
    o[0] = (short)f2bf(a.x); o[1] = (short)f2bf(a.y);
    o[2] = (short)f2bf(a.z); o[3] = (short)f2bf(a.w);
    o[4] = (short)f2bf(c.x); o[5] = (short)f2bf(c.y);
    o[6] = (short)f2bf(c.z); o[7] = (short)f2bf(c.w);
    ((bf8*)single_bf)[idx] = o;
  } else if (b < 156) {
    wfrag_dev(W_qkv, WallFrag, 384, 576, 1.f, b - 144, 0, 72, Ws, t);
  } else if (b < 168) {
    wfrag_dev(W_qkp, WallFrag, 384, 288, 1.f, b - 156, 36, 72, Ws, t);
  } else if (b < 180) {
    wfrag_dev(W_vp, WallFrag, 384, 288, 1.f, b - 168, 54, 72, Ws, t);
  } else if (b < 184) {
    wfrag_dev(W_b, WbFrag, 128, 12, W_L_, b - 180, 0, 1, Ws, t);
  } else {
    wfrag_dev(W_out, WoutFrag, 2112, 384, 1.f, b - 184, 0, 24, Ws, t);
  }
}

// ---------------------------------------------------------------------------
// bf16 MFMA GEMM (pre-fragmented B direct from global), BM=64 BN=32.
// ---------------------------------------------------------------------------
__global__ __launch_bounds__(256) void mfma_gemm(
    const u16* __restrict__ Abf, const u16* __restrict__ Bfrag,
    const float* __restrict__ bias, float* __restrict__ C,
    int M, int N, int K, int ldc) {
  __shared__ u16 As[64 * 32];
  const int t = threadIdx.x, w = t >> 6, l = t & 63;
  const int bi = blockIdx.y * 64, nt0 = blockIdx.x * 2;
  const int NT = N >> 4, KS = K >> 5;
  v4f acc0 = {0.f, 0.f, 0.f, 0.f}, acc1 = {0.f, 0.f, 0.f, 0.f};
  const int srow = t >> 2, sc = t & 3;
  const int wslot = (sc ^ (srow & 3)) * 8;
  const bf8* Bf = (const bf8*)Bfrag;

  bf8 areg = *(const bf8*)(Abf + (size_t)(bi + srow) * K + sc * 8);
  bf8 b0 = Bf[(size_t)(0 * NT + nt0) * 64 + l];
  bf8 b1 = Bf[(size_t)(0 * NT + nt0 + 1) * 64 + l];
  const int rdoff = (w * 16 + (l & 15)) * 32 + (((l >> 4) ^ (l & 3)) * 8);
  for (int ks = 0; ks < KS; ks++) {
    *(bf8*)&As[srow * 32 + wslot] = areg;
    bf8 an, bn0, bn1;
    if (ks + 1 < KS) {
      an = *(const bf8*)(Abf + (size_t)(bi + srow) * K + (ks + 1) * 32 + sc * 8);
      bn0 = Bf[(size_t)((ks + 1) * NT + nt0) * 64 + l];
      bn1 = Bf[(size_t)((ks + 1) * NT + nt0 + 1) * 64 + l];
    }
    __syncthreads();
    bf8 af = *(const bf8*)&As[rdoff];
    acc0 = __builtin_amdgcn_mfma_f32_16x16x32_bf16(af, b0, acc0, 0, 0, 0);
    acc1 = __builtin_amdgcn_mfma_f32_16x16x32_bf16(af, b1, acc1, 0, 0, 0);
    __syncthreads();
    areg = an; b0 = bn0; b1 = bn1;
  }
  int col0 = nt0 * 16 + (l & 15), col1 = col0 + 16;
  float bb0 = bias ? bias[col0] : 0.f;
  float bb1 = bias ? bias[col1] : 0.f;
#pragma unroll
  for (int r = 0; r < 4; r++) {
    int row = bi + w * 16 + (l >> 4) * 4 + r;
    C[(size_t)row * ldc + col0] = acc0[r] + bb0;
    C[(size_t)row * ldc + col1] = acc1[r] + bb1;
  }
}

// ---------------------------------------------------------------------------
// Prep: reshape projAll [n][1152] (qkv | qkp | vp), apply frames.
// qbuf/kbuf [n][h*16+c]; v2buf [n][h*40+e]; qgbuf/kgbuf [n][h*12+e];
// sqbuf/skbuf [n][12].
// ---------------------------------------------------------------------------
__global__ __launch_bounds__(256) void prep_kernel(
    const float* __restrict__ projAll, const float* __restrict__ fR,
    const float* __restrict__ ft,
    float* __restrict__ qbuf, float* __restrict__ kbuf, float* __restrict__ v2buf,
    float* __restrict__ qgbuf, float* __restrict__ kgbuf,
    float* __restrict__ sqbuf, float* __restrict__ skbuf) {
  const int n = blockIdx.x, t = threadIdx.x;
  __shared__ float R[9], tt[3];
  __shared__ float qgL[144], kgL[144];
  if (t < 9) R[t] = fR[n * 9 + t];
  if (t < 3) tt[t] = ft[n * 3 + t];
  __syncthreads();
  const float* rQKV = projAll + (size_t)n * 1152;
  const float* rQKP = rQKV + 576;
  const float* rVP = rQKV + 864;
  if (t < 192) {
    int h = t >> 4, c = t & 15;
    qbuf[(size_t)n * 192 + t] = rQKV[c * 12 + h];
    kbuf[(size_t)n * 192 + t] = rQKV[192 + c * 12 + h];
    v2buf[(size_t)n * 480 + h * 40 + c] = rQKV[384 + c * 12 + h];
  }
  if (t < 144) {
    int e = t / 12, h = t % 12;
    int p = e / 3, x = e % 3;
    float aq = tt[x], ak = tt[x];
#pragma unroll
    for (int y = 0; y < 3; y++) {
      float r = R[x * 3 + y];
      aq += r * rQKP[p * 36 + y * 12 + h];
      ak += r * rQKP[144 + p * 36 + y * 12 + h];
    }
    qgL[h * 12 + e] = aq;
    kgL[h * 12 + e] = ak;
    qgbuf[(size_t)n * 144 + h * 12 + e] = aq;
    kgbuf[(size_t)n * 144 + h * 12 + e] = ak;
  }
  for (int idx = t; idx < 288; idx += 256) {
    int e = idx / 12, h = idx % 12;
    int p = e / 3, x = e % 3;
    float a = tt[x];
#pragma unroll
    for (int y = 0; y < 3; y++) a += R[x * 3 + y] * rVP[p * 36 + y * 12 + h];
    v2buf[(size_t)n * 480 + h * 40 + 16 + e] = a;
  }
  __syncthreads();
  if (t < 12) {
    float s = 0.f;
#pragma unroll
    for (int e = 0; e < 12; e++) { float v = qgL[t * 12 + e]; s += v * v; }
    sqbuf[n * 12 + t] = s;
  } else if (t < 24) {
    int h = t - 12;
    float s = 0.f;
#pragma unroll
    for (int e = 0; e < 12; e++) { float v = kgL[h * 12 + e]; s += v * v; }
    skbuf[n * 12 + h] = s;
  }
}

// ---------------------------------------------------------------------------
// Pair pass 1: bias MFMA + full logits (f32). bf16 pair copy is stored at the
// END of the kernel (off the barrier critical path). Grid (12 jt, 768 i).
// ---------------------------------------------------------------------------
__global__ __launch_bounds__(256) void biaslogit_k(
    const float* __restrict__ pair, const u16* __restrict__ WbFrag,
    const float* __restrict__ gamma,
    const float* __restrict__ qbuf, const float* __restrict__ kbuf,
    const float* __restrict__ qgbuf, const float* __restrict__ kgbuf,
    const float* __restrict__ sqbuf, const float* __restrict__ skbuf,
    u16* __restrict__ pair_bf, float* __restrict__ logits) {
  const int jt = blockIdx.x, i = blockIdx.y;
  const int t = threadIdx.x, w = t >> 6, l = t & 63;
  __shared__ u16 pS[64 * 128];
  __shared__ float lgL[64 * 15];
  __shared__ float qL[192], qgL[144], c1L[12], c2L[12];

  if (t < 192) qL[t] = qbuf[(size_t)i * 192 + t];
  if (t < 144) qgL[t] = qgbuf[(size_t)i * 144 + t];
  if (t < 12) {
    float g = gamma[t];
    float hw = fmaxf(g, 0.f) + log1pf(expf(-fabsf(g)));
    c1L[t] = W_L_ * W_C_ * hw;
    c2L[t] = -0.5f * c1L[t] * sqbuf[i * 12 + t];
  }
  bf8 wb[4];
  const bf8* Wf = (const bf8*)WbFrag;
#pragma unroll
  for (int ks = 0; ks < 4; ks++) wb[ks] = Wf[ks * 64 + l];

  // stage pair tile -> swizzled bf16 LDS (no global store here)
  const float* pg = pair + ((size_t)i * 768 + jt * 64) * 128;
#pragma unroll
  for (int it = 0; it < 4; it++) {
    int idx = t + 256 * it;
    int j = idx >> 4, c = idx & 15;
    v4f x0 = *(const v4f*)(pg + j * 128 + c * 8);
    v4f x1 = *(const v4f*)(pg + j * 128 + c * 8 + 4);
    bf8 pk;
    pk[0] = (short)f2bf(x0.x); pk[1] = (short)f2bf(x0.y);
    pk[2] = (short)f2bf(x0.z); pk[3] = (short)f2bf(x0.w);
    pk[4] = (short)f2bf(x1.x); pk[5] = (short)f2bf(x1.y);
    pk[6] = (short)f2bf(x1.z); pk[7] = (short)f2bf(x1.w);
    *(bf8*)&pS[j * 128 + ((c ^ (j & 15)) * 8)] = pk;
  }
  __syncthreads();

  // MFMA: W_L * (pair @ W_b) -> lgL[j][h]
  {
    v4f acc = {0.f, 0.f, 0.f, 0.f};
#pragma unroll
    for (int ks = 0; ks < 4; ks++) {
      int slot = (ks * 4 + (l >> 4)) ^ (l & 15);
      bf8 af = *(const bf8*)&pS[(w * 16 + (l & 15)) * 128 + slot * 8];
      acc = __builtin_amdgcn_mfma_f32_16x16x32_bf16(af, wb[ks], acc, 0, 0, 0);
    }
    int h = l & 15;
    if (h < 12) {
#pragma unroll
      for (int r = 0; r < 4; r++)
        lgL[(w * 16 + (l >> 4) * 4 + r) * 15 + h] = acc[r];
    }
  }
  __syncthreads();

  // qk + point-dist terms in f32 (k-side from L2)
  {
    const int j = t >> 2, hg = t & 3;
    const int jg = jt * 64 + j;
#pragma unroll
    for (int hh = 0; hh < 3; hh++) {
      int h = hg * 3 + hh;
      const v4f* kk = (const v4f*)(kbuf + (size_t)jg * 192 + h * 16);
      const v4f* qq = (const v4f*)&qL[h * 16];
      float qk = dot4(kk[0], qq[0]) + dot4(kk[1], qq[1]) +
                 dot4(kk[2], qq[2]) + dot4(kk[3], qq[3]);
      const v4f* kg = (const v4f*)(kgbuf + (size_t)jg * 144 + h * 12);
      const v4f* qg = (const v4f*)&qgL[h * 12];
      float cr = dot4(kg[0], qg[0]) + dot4(kg[1], qg[1]) + dot4(kg[2], qg[2]);
      float sk = skbuf[(size_t)jg * 12 + h];
      lgL[j * 15 + h] += 0.25f * W_L_ * qk + c1L[h] * (cr - 0.5f * sk) + c2L[h];
    }
  }
  __syncthreads();

  // write logits [i][h][jt*64+j], coalesced in j
#pragma unroll
  for (int s = 0; s < 3; s++) {
    int o = t + 256 * s;
    int h = o >> 6, j = o & 63;
    logits[((size_t)i * 12 + h) * 768 + jt * 64 + j] = lgL[j * 15 + h];
  }

  // tail: bf16 pair copy from LDS (no barrier after; drains at endpgm)
  u16* pbg = pair_bf + ((size_t)i * 768 + jt * 64) * 128;
#pragma unroll
  for (int it = 0; it < 4; it++) {
    int idx = t + 256 * it;
    int j = idx >> 4, c = idx & 15;
    bf8 pk = *(const bf8*)&pS[j * 128 + ((c ^ (j & 15)) * 8)];
    *(bf8*)(pbg + j * 128 + c * 8) = pk;
  }
}

// ---------------------------------------------------------------------------
// Softmax over j: one wave per (i,h) row of 768 f32 -> bf16 attn. Grid 2304.
// ---------------------------------------------------------------------------
__global__ __launch_bounds__(256) void softmax_bf(const float* __restrict__ L,
                                                  u16* __restrict__ attn) {
  const int row = blockIdx.x * 4 + (threadIdx.x >> 6);
  const int lane = threadIdx.x & 63;
  const v4f* p = (const v4f*)(L + (size_t)row * 768);
  v4f a0 = p[lane], a1 = p[lane + 64], a2 = p[lane + 128];
  float m0 = fmaxf(fmaxf(a0.x, a0.y), fmaxf(a0.z, a0.w));
  float m1 = fmaxf(fmaxf(a1.x, a1.y), fmaxf(a1.z, a1.w));
  float m2 = fmaxf(fmaxf(a2.x, a2.y), fmaxf(a2.z, a2.w));
  float m = fmaxf(m0, fmaxf(m1, m2));
#pragma unroll
  for (int s = 32; s >= 1; s >>= 1) m = fmaxf(m, __shfl_xor(m, s));
  a0.x = __expf(a0.x - m); a0.y = __expf(a0.y - m);
  a0.z = __expf(a0.z - m); a0.w = __expf(a0.w - m);
  a1.x = __expf(a1.x - m); a1.y = __expf(a1.y - m);
  a1.z = __expf(a1.z - m); a1.w = __expf(a1.w - m);
  a2.x = __expf(a2.x - m); a2.y = __expf(a2.y - m);
  a2.z = __expf(a2.z - m); a2.w = __expf(a2.w - m);
  float s = a0.x + a0.y + a0.z + a0.w + a1.x + a1.y + a1.z + a1.w +
            a2.x + a2.y + a2.z + a2.w;
#pragma unroll
  for (int q = 32; q >= 1; q >>= 1) s += __shfl_xor(s, q);
  float inv = 1.f / s;
  a0 *= inv; a1 *= inv; a2 *= inv;
  u16* arow = attn + (size_t)row * 768;
  uint2 pk;
  pk.x = (unsigned)f2bf(a0.x) | ((unsigned)f2bf(a0.y) << 16);
  pk.y = (unsigned)f2bf(a0.z) | ((unsigned)f2bf(a0.w) << 16);
  *(uint2*)&arow[lane * 4] = pk;
  pk.x = (unsigned)f2bf(a1.x) | ((unsigned)f2bf(a1.y) << 16);
  pk.y = (unsigned)f2bf(a1.z) | ((unsigned)f2bf(a1.w) << 16);
  *(uint2*)&arow[256 + lane * 4] = pk;
  pk.x = (unsigned)f2bf(a2.x) | ((unsigned)f2bf(a2.y) << 16);
  pk.y = (unsigned)f2bf(a2.z) | ((unsigned)f2bf(a2.w) << 16);
  *(uint2*)&arow[512 + lane * 4] = pk;
}

// ---------------------------------------------------------------------------
// Pair pass 2 (bf16, L3-resident): o_pair -> feats[:,0:1536].
// ---------------------------------------------------------------------------
__global__ __launch_bounds__(256) void opair_k(
    const u16* __restrict__ pair_bf, const u16* __restrict__ attn,
    u16* __restrict__ feats_bf) {
  const int i = blockIdx.x, t = threadIdx.x;
  const int w = t >> 6, l = t & 63;
  const int dq = l & 31, hh = l >> 5;
  __shared__ float smemf[6160];          // 24.6 KB, overlaid regions
  u16* pS = (u16*)smemf;                 // [64*128] bf16 swizzled (16 KB)
  float* ALf = smemf + 4096;             // [12][68]
  float* red = smemf;                    // reduction overlay (6144 f)

  v4f acc[6];
#pragma unroll
  for (int k = 0; k < 6; k++) acc[k] = (v4f){0.f, 0.f, 0.f, 0.f};

  bf8 pr[4];
  bf8 areg;
  {
    const u16* pg = pair_bf + (size_t)i * 768 * 128;
#pragma unroll
    for (int it = 0; it < 4; it++) {
      int idx = t + 256 * it;
      pr[it] = *(const bf8*)(pg + (idx >> 4) * 128 + (idx & 15) * 8);
    }
    if (t < 96)
      areg = *(const bf8*)(attn + ((size_t)i * 12 + (t >> 3)) * 768 + (t & 7) * 8);
  }
  for (int jt = 0; jt < 12; jt++) {
#pragma unroll
    for (int it = 0; it < 4; it++) {
      int idx = t + 256 * it;
      int j = idx >> 4, c = idx & 15;
      *(bf8*)&pS[j * 128 + ((c ^ (j & 15)) * 8)] = pr[it];
    }
    if (t < 96) {
      int hA = t >> 3, c = t & 7;
#pragma unroll
      for (int e = 0; e < 8; e++) ALf[hA * 68 + c * 8 + e] = bf2f((u16)areg[e]);
    }
    if (jt < 11) {
      const u16* pg = pair_bf + ((size_t)i * 768 + (jt + 1) * 64) * 128;
#pragma unroll
      for (int it = 0; it < 4; it++) {
        int idx = t + 256 * it;
        pr[it] = *(const bf8*)(pg + (idx >> 4) * 128 + (idx & 15) * 8);
      }
      if (t < 96)
        areg = *(const bf8*)(attn + ((size_t)i * 12 + (t >> 3)) * 768 +
                             (jt + 1) * 64 + (t & 7) * 8);
    }
    __syncthreads();
#pragma unroll
    for (int jj16 = 0; jj16 < 16; jj16++) {
      int jj = w * 16 + jj16;
      const u16* pv4 = &pS[jj * 128 + (((dq >> 1) ^ (jj & 15)) * 8) + (dq & 1) * 4];
      v4f pv;
      pv.x = bf2f(pv4[0]); pv.y = bf2f(pv4[1]);
      pv.z = bf2f(pv4[2]); pv.w = bf2f(pv4[3]);
      float a0 = ALf[(hh * 6 + 0) * 68 + jj];
      float a1 = ALf[(hh * 6 + 1) * 68 + jj];
      float a2 = ALf[(hh * 6 + 2) * 68 + jj];
      float a3 = ALf[(hh * 6 + 3) * 68 + jj];
      float a4 = ALf[(hh * 6 + 4) * 68 + jj];
      float a5 = ALf[(hh * 6 + 5) * 68 + jj];
      acc[0] += pv * a0; acc[1] += pv * a1; acc[2] += pv * a2;
      acc[3] += pv * a3; acc[4] += pv * a4; acc[5] += pv * a5;
    }
    __syncthreads();
  }
  // cross-wave reduction
#pragma unroll
  for (int k = 0; k < 6; k++)
    *(v4f*)&red[(w * 12 + hh * 6 + k) * 128 + dq * 4] = acc[k];
  __syncthreads();
  const size_t fb = (size_t)i * 2112;
#pragma unroll
  for (int s = 0; s < 6; s++) {
    int o = t + 256 * s;
    int ho = o >> 7, dd = o & 127;
    float v = red[ho * 128 + dd] + red[(12 + ho) * 128 + dd] +
              red[(24 + ho) * 128 + dd] + red[(36 + ho) * 128 + dd];
    feats_bf[fb + o] = f2bf(v);
  }
}

// ---------------------------------------------------------------------------
// o / og + finalize fused: per (i-tile of 64, h). Accumulate over j, then
// rotate into local frame + norms, write feats[:,1536:2112] directly.
// ---------------------------------------------------------------------------
__global__ __launch_bounds__(256) void ovfin_k(
    const u16* __restrict__ attn, const float* __restrict__ v2buf,
    const float* __restrict__ fR, const float* __restrict__ ft,
    u16* __restrict__ feats_bf) {
  const int i0 = blockIdx.x * 64, h = blockIdx.y, t = threadIdx.x;
  __shared__ float AL[64][65];
  __shared__ float VL[64][48];
  const int il = t & 63, eb = (t >> 6) * 12;
  v4f acc0 = {0.f, 0.f, 0.f, 0.f}, acc1 = {0.f, 0.f, 0.f, 0.f},
      acc2 = {0.f, 0.f, 0.f, 0.f};
  for (int jt = 0; jt < 12; ++jt) {
    const int j0 = jt * 64;
#pragma unroll
    for (int q = 0; q < 2; q++) {
      int idx = t + 256 * q;
      int ii = idx >> 3, c = idx & 7;
      bf8 av = *(const bf8*)(attn + ((size_t)(i0 + ii) * 12 + h) * 768 + j0 + c * 8);
#pragma unroll
      for (int e = 0; e < 8; e++) AL[ii][c * 8 + e] = bf2f((u16)av[e]);
    }
#pragma unroll
    for (int q = 0; q < 3; q++) {
      int idx = t + q * 256;
      if (idx < 640) {
        int jj = idx / 10, e4 = idx % 10;
        *(v4f*)&VL[jj][e4 * 4] =
            *(const v4f*)(v2buf + (size_t)(j0 + jj) * 480 + h * 40 + e4 * 4);
      }
    }
    __syncthreads();
#pragma unroll 4
    for (int jj = 0; jj < 64; ++jj) {
      float a = AL[il][jj];
      v4f v0 = *(const v4f*)&VL[jj][eb];
      v4f v1 = *(const v4f*)&VL[jj][eb + 4];
      v4f v2 = *(const v4f*)&VL[jj][eb + 8];
      acc0 += v0 * a;
      acc1 += v1 * a;
      acc2 += v2 * a;
    }
    __syncthreads();
  }
  // stage per-i O row into LDS (reuse AL region)
  float* OL = &AL[0][0];  // [64][44]
#pragma unroll
  for (int s = 0; s < 12; ++s) {
    int e = eb + s;
    if (e < 40) {
      float v = (s < 4) ? ((float*)&acc0)[s]
                        : (s < 8) ? ((float*)&acc1)[s - 4] : ((float*)&acc2)[s - 8];
      OL[il * 44 + e] = v;
    }
  }
  __syncthreads();
  // finalize: 4 threads per i
  {
    const int ii = t >> 2, sub = t & 3;
    const int ig = i0 + ii;
    const float* orow = &OL[ii * 44];
    const size_t fb = (size_t)ig * 2112;
    if (sub == 0) {
#pragma unroll
      for (int c = 0; c < 16; c++)
        feats_bf[fb + 1536 + h * 16 + c] = f2bf(orow[c]);
    } else {
      float R[9], tt[3];
#pragma unroll
      for (int k = 0; k < 9; k++) R[k] = fR[ig * 9 + k];
#pragma unroll
      for (int k = 0; k < 3; k++) tt[k] = ft[ig * 3 + k];
      int p0 = (sub - 1) * 3, pn = (sub == 3) ? 2 : 3;
#pragma unroll
      for (int pp = 0; pp < 3; pp++) {
        if (pp < pn) {
          int p = p0 + pp;
          float og0 = orow[16 + p * 3 + 0] - tt[0];
          float og1 = orow[16 + p * 3 + 1] - tt[1];
          float og2 = orow[16 + p * 3 + 2] - tt[2];
          float o0 = R[0] * og0 + R[3] * og1 + R[6] * og2;
          float o1 = R[1] * og0 + R[4] * og1 + R[7] * og2;
          float o2 = R[2] * og0 + R[5] * og1 + R[8] * og2;
          feats_bf[fb + 1728 + h * 24 + p * 3 + 0] = f2bf(o0);
          feats_bf[fb + 1728 + h * 24 + p * 3 + 1] = f2bf(o1);
          feats_bf[fb + 1728 + h * 24 + p * 3 + 2] = f2bf(o2);
          feats_bf[fb + 2016 + h * 8 + p] =
              f2bf(sqrtf(o0 * o0 + o1 * o1 + o2 * o2 + 1e-8f));
        }
      }
    }
  }
}

// ---------------------------------------------------------------------------
extern "C" void kernel_launch(void* const* d_in, const int* in_sizes, int n_in,
                              void* d_out, int out_size, void* d_ws, size_t ws_size,
                              hipStream_t stream) {
  const float* single = (const float*)d_in[0];
  const float* pair = (const float*)d_in[1];
  const float* fR = (const float*)d_in[2];
  const float* ft = (const float*)d_in[3];
  const float* W_qkv = (const float*)d_in[4];
  const float* W_b = (const float*)d_in[5];
  const float* W_qkp = (const float*)d_in[6];
  const float* W_vp = (const float*)d_in[7];
  const float* gamma = (const float*)d_in[8];
  const float* W_out = (const float*)d_in[9];
  const float* b_out = (const float*)d_in[10];
  float* out = (float*)d_out;

  float* ws = (float*)d_ws;
  float* projAll = ws;                      // 884736 (768*1152)
  float* qbuf    = ws + 884736;             // 147456
  float* kbuf    = ws + 1032192;            // 147456
  float* v2buf   = ws + 1179648;            // 368640
  float* qgbuf   = ws + 1548288;            // 110592
  float* kgbuf   = ws + 1658880;            // 110592
  float* sqbuf   = ws + 1769472;            // 9216
  float* skbuf   = ws + 1778688;            // 9216
  float* logits  = ws + 1787904;            // 7077888
  u16* ub        = (u16*)(ws + 8865792);
  u16* single_bf = ub;                      // 294912
  u16* WallFrag  = ub + 294912;             // 442368 (12 ks * 72 nt * 512)
  u16* WbFrag    = ub + 737280;             // 2048
  u16* WoutFrag  = ub + 739328;             // 811008
  u16* attn      = ub + 1550336;            // 7077888
  u16* feats_bf  = ub + 8628224;            // 1622016
  u16* pair_bf   = ub + 10250240;           // 75497472

  // fused conversions + weight fragmenting (1 launch)
  wfrag_all<<<250, 256, 0, stream>>>(single, single_bf, W_qkv, W_qkp, W_vp,
                                     W_b, W_out, WallFrag, WbFrag, WoutFrag);
  // all projections in one MFMA GEMM (N = 576+288+288 = 1152)
  mfma_gemm<<<dim3(36, 12), 256, 0, stream>>>(single_bf, WallFrag, nullptr,
                                              projAll, 768, 1152, 384, 1152);
  // reshape + frames
  prep_kernel<<<768, 256, 0, stream>>>(projAll, fR, ft, qbuf, kbuf, v2buf,
                                       qgbuf, kgbuf, sqbuf, skbuf);
  // pair pass 1: bias MFMA + logits (+ tail bf16 pair copy)
  biaslogit_k<<<dim3(12, 768), 256, 0, stream>>>(pair, WbFrag, gamma, qbuf, kbuf,
                                                 qgbuf, kgbuf, sqbuf, skbuf,
                                                 pair_bf, logits);
  // softmax -> attn bf16
  softmax_bf<<<2304, 256, 0, stream>>>(logits, attn);
  // pair pass 2: o_pair
  opair_k<<<768, 256, 0, stream>>>(pair_bf, attn, feats_bf);
  // o / og + finalize
  ovfin_k<<<dim3(12, 12), 256, 0, stream>>>(attn, v2buf, fR, ft, feats_bf);
  // output projection (bf16 MFMA)
  mfma_gemm<<<dim3(12, 12), 256, 0, stream>>>(feats_bf, WoutFrag, b_out,
                                              out, 768, 384, 2112, 384);
}

// Round 9
// 296.375 us; speedup vs baseline: 1.3203x; 1.0017x over previous
//
#include <hip/hip_runtime.h>
#include <hip/hip_bf16.h>

typedef float v4f __attribute__((ext_vector_type(4)));
typedef short bf8 __attribute__((ext_vector_type(8)));  // 8 bf16 in 4 VGPRs
typedef unsigned short u16;

constexpr float W_C_ = 0.23570226039551584f;  // sqrt(2/(9*4))
constexpr float W_L_ = 0.5773502691896258f;   // sqrt(1/3)

__device__ __forceinline__ u16 f2bf(float f) {  // RNE f32->bf16
  unsigned u = __float_as_uint(f);
  return (u16)((u + 0x7FFFu + ((u >> 16) & 1u)) >> 16);
}
__device__ __forceinline__ float bf2f(u16 h) {
  return __uint_as_float(((unsigned)h) << 16);
}
__device__ __forceinline__ float dot4(v4f a, v4f b) {
  return a.x * b.x + a.y * b.y + a.z * b.z + a.w * b.w;
}

// ---------------------------------------------------------------------------
// Fused weight prep: blocks [0,144) convert single->bf16; the rest fragment
// W_qkv/W_qkp/W_vp (into one combined frag, N=1152), W_b, W_out.
// ---------------------------------------------------------------------------
__device__ void wfrag_dev(const float* __restrict__ W, u16* __restrict__ frag,
                          int K, int N, float scale, int ks, int ntBase,
                          int NTtotal, float* Ws, int t) {
  const int k0 = ks * 32;
  for (int n0 = 0; n0 < N; n0 += 384) {
    int PN = N - n0; if (PN > 384) PN = 384;
    __syncthreads();
    for (int idx = t; idx < 32 * PN; idx += 256) {
      int r = idx / PN, c = idx - r * PN;
      Ws[r * PN + c] = W[(size_t)(k0 + r) * N + n0 + c];
    }
    __syncthreads();
    int NTp = (PN + 15) >> 4;
    for (int c = t; c < NTp * 64; c += 256) {
      int nt = c >> 6, l = c & 63;
      int col = nt * 16 + (l & 15);
      bf8 o;
#pragma unroll
      for (int e = 0; e < 8; e++) {
        int rr = (l >> 4) * 8 + e;
        float f = (col < PN) ? Ws[rr * PN + col] * scale : 0.f;
        o[e] = (short)f2bf(f);
      }
      ((bf8*)frag)[((size_t)ks * NTtotal + ntBase + (n0 >> 4) + nt) * 64 + l] = o;
    }
  }
}

__global__ __launch_bounds__(256) void wfrag_all(
    const float* __restrict__ single, u16* __restrict__ single_bf,
    const float* __restrict__ W_qkv, const float* __restrict__ W_qkp,
    const float* __restrict__ W_vp, const float* __restrict__ W_b,
    const float* __restrict__ W_out,
    u16* __restrict__ WallFrag, u16* __restrict__ WbFrag,
    u16* __restrict__ WoutFrag) {
  __shared__ float Ws[32 * 384];
  const int b = blockIdx.x, t = threadIdx.x;
  if (b < 144) {  // convert single (294912 f32) to bf16, 8 per thread
    int idx = b * 256 + t;
    v4f a = ((const v4f*)single)[idx * 2];
    v4f c = ((const v4f*)single)[idx * 2 + 1];
    bf8 o;
    o[0] = (short)f2bf(a.x); o[1] = (short)f2bf(a.y);
    o[2] = (short)f2bf(a.z); o[3] = (short)f2bf(a.w);
    o[4] = (short)f2bf(c.x); o[5] = (short)f2bf(c.y);
    o[6] = (short)f2bf(c.z); o[7] = (short)f2bf(c.w);
    ((bf8*)single_bf)[idx] = o;
  } else if (b < 156) {
    wfrag_dev(W_qkv, WallFrag, 384, 576, 1.f, b - 144, 0, 72, Ws, t);
  } else if (b < 168) {
    wfrag_dev(W_qkp, WallFrag, 384, 288, 1.f, b - 156, 36, 72, Ws, t);
  } else if (b < 180) {
    wfrag_dev(W_vp, WallFrag, 384, 288, 1.f, b - 168, 54, 72, Ws, t);
  } else if (b < 184) {
    wfrag_dev(W_b, WbFrag, 128, 12, W_L_, b - 180, 0, 1, Ws, t);
  } else {
    wfrag_dev(W_out, WoutFrag, 2112, 384, 1.f, b - 184, 0, 24, Ws, t);
  }
}

// ---------------------------------------------------------------------------
// bf16 MFMA GEMM (pre-fragmented B direct from global), BM=64 BN=32.
// ---------------------------------------------------------------------------
__global__ __launch_bounds__(256) void mfma_gemm(
    const u16* __restrict__ Abf, const u16* __restrict__ Bfrag,
    const float* __restrict__ bias, float* __restrict__ C,
    int M, int N, int K, int ldc) {
  __shared__ u16 As[64 * 32];
  const int t = threadIdx.x, w = t >> 6, l = t & 63;
  const int bi = blockIdx.y * 64, nt0 = blockIdx.x * 2;
  const int NT = N >> 4, KS = K >> 5;
  v4f acc0 = {0.f, 0.f, 0.f, 0.f}, acc1 = {0.f, 0.f, 0.f, 0.f};
  const int srow = t >> 2, sc = t & 3;
  const int wslot = (sc ^ (srow & 3)) * 8;
  const bf8* Bf = (const bf8*)Bfrag;

  bf8 areg = *(const bf8*)(Abf + (size_t)(bi + srow) * K + sc * 8);
  bf8 b0 = Bf[(size_t)(0 * NT + nt0) * 64 + l];
  bf8 b1 = Bf[(size_t)(0 * NT + nt0 + 1) * 64 + l];
  const int rdoff = (w * 16 + (l & 15)) * 32 + (((l >> 4) ^ (l & 3)) * 8);
  for (int ks = 0; ks < KS; ks++) {
    *(bf8*)&As[srow * 32 + wslot] = areg;
    bf8 an, bn0, bn1;
    if (ks + 1 < KS) {
      an = *(const bf8*)(Abf + (size_t)(bi + srow) * K + (ks + 1) * 32 + sc * 8);
      bn0 = Bf[(size_t)((ks + 1) * NT + nt0) * 64 + l];
      bn1 = Bf[(size_t)((ks + 1) * NT + nt0 + 1) * 64 + l];
    }
    __syncthreads();
    bf8 af = *(const bf8*)&As[rdoff];
    acc0 = __builtin_amdgcn_mfma_f32_16x16x32_bf16(af, b0, acc0, 0, 0, 0);
    acc1 = __builtin_amdgcn_mfma_f32_16x16x32_bf16(af, b1, acc1, 0, 0, 0);
    __syncthreads();
    areg = an; b0 = bn0; b1 = bn1;
  }
  int col0 = nt0 * 16 + (l & 15), col1 = col0 + 16;
  float bb0 = bias ? bias[col0] : 0.f;
  float bb1 = bias ? bias[col1] : 0.f;
#pragma unroll
  for (int r = 0; r < 4; r++) {
    int row = bi + w * 16 + (l >> 4) * 4 + r;
    C[(size_t)row * ldc + col0] = acc0[r] + bb0;
    C[(size_t)row * ldc + col1] = acc1[r] + bb1;
  }
}

// ---------------------------------------------------------------------------
// Prep: reshape projAll [n][1152] (qkv | qkp | vp), apply frames.
// ---------------------------------------------------------------------------
__global__ __launch_bounds__(256) void prep_kernel(
    const float* __restrict__ projAll, const float* __restrict__ fR,
    const float* __restrict__ ft,
    float* __restrict__ qbuf, float* __restrict__ kbuf, float* __restrict__ v2buf,
    float* __restrict__ qgbuf, float* __restrict__ kgbuf,
    float* __restrict__ sqbuf, float* __restrict__ skbuf) {
  const int n = blockIdx.x, t = threadIdx.x;
  __shared__ float R[9], tt[3];
  __shared__ float qgL[144], kgL[144];
  if (t < 9) R[t] = fR[n * 9 + t];
  if (t < 3) tt[t] = ft[n * 3 + t];
  __syncthreads();
  const float* rQKV = projAll + (size_t)n * 1152;
  const float* rQKP = rQKV + 576;
  const float* rVP = rQKV + 864;
  if (t < 192) {
    int h = t >> 4, c = t & 15;
    qbuf[(size_t)n * 192 + t] = rQKV[c * 12 + h];
    kbuf[(size_t)n * 192 + t] = rQKV[192 + c * 12 + h];
    v2buf[(size_t)n * 480 + h * 40 + c] = rQKV[384 + c * 12 + h];
  }
  if (t < 144) {
    int e = t / 12, h = t % 12;
    int p = e / 3, x = e % 3;
    float aq = tt[x], ak = tt[x];
#pragma unroll
    for (int y = 0; y < 3; y++) {
      float r = R[x * 3 + y];
      aq += r * rQKP[p * 36 + y * 12 + h];
      ak += r * rQKP[144 + p * 36 + y * 12 + h];
    }
    qgL[h * 12 + e] = aq;
    kgL[h * 12 + e] = ak;
    qgbuf[(size_t)n * 144 + h * 12 + e] = aq;
    kgbuf[(size_t)n * 144 + h * 12 + e] = ak;
  }
  for (int idx = t; idx < 288; idx += 256) {
    int e = idx / 12, h = idx % 12;
    int p = e / 3, x = e % 3;
    float a = tt[x];
#pragma unroll
    for (int y = 0; y < 3; y++) a += R[x * 3 + y] * rVP[p * 36 + y * 12 + h];
    v2buf[(size_t)n * 480 + h * 40 + 16 + e] = a;
  }
  __syncthreads();
  if (t < 12) {
    float s = 0.f;
#pragma unroll
    for (int e = 0; e < 12; e++) { float v = qgL[t * 12 + e]; s += v * v; }
    sqbuf[n * 12 + t] = s;
  } else if (t < 24) {
    int h = t - 12;
    float s = 0.f;
#pragma unroll
    for (int e = 0; e < 12; e++) { float v = kgL[h * 12 + e]; s += v * v; }
    skbuf[n * 12 + h] = s;
  }
}

// ---------------------------------------------------------------------------
// Pair pass 1: bias MFMA + full logits (f32). bf16 pair copy stored at the
// END (off the barrier critical path). Grid (12 jt, 768 i).
// ---------------------------------------------------------------------------
__global__ __launch_bounds__(256) void biaslogit_k(
    const float* __restrict__ pair, const u16* __restrict__ WbFrag,
    const float* __restrict__ gamma,
    const float* __restrict__ qbuf, const float* __restrict__ kbuf,
    const float* __restrict__ qgbuf, const float* __restrict__ kgbuf,
    const float* __restrict__ sqbuf, const float* __restrict__ skbuf,
    u16* __restrict__ pair_bf, float* __restrict__ logits) {
  const int jt = blockIdx.x, i = blockIdx.y;
  const int t = threadIdx.x, w = t >> 6, l = t & 63;
  __shared__ u16 pS[64 * 128];
  __shared__ float lgL[64 * 15];
  __shared__ float qL[192], qgL[144], c1L[12], c2L[12];

  if (t < 192) qL[t] = qbuf[(size_t)i * 192 + t];
  if (t < 144) qgL[t] = qgbuf[(size_t)i * 144 + t];
  if (t < 12) {
    float g = gamma[t];
    float hw = fmaxf(g, 0.f) + log1pf(expf(-fabsf(g)));
    c1L[t] = W_L_ * W_C_ * hw;
    c2L[t] = -0.5f * c1L[t] * sqbuf[i * 12 + t];
  }
  bf8 wb[4];
  const bf8* Wf = (const bf8*)WbFrag;
#pragma unroll
  for (int ks = 0; ks < 4; ks++) wb[ks] = Wf[ks * 64 + l];

  // stage pair tile -> swizzled bf16 LDS (no global store here)
  const float* pg = pair + ((size_t)i * 768 + jt * 64) * 128;
#pragma unroll
  for (int it = 0; it < 4; it++) {
    int idx = t + 256 * it;
    int j = idx >> 4, c = idx & 15;
    v4f x0 = *(const v4f*)(pg + j * 128 + c * 8);
    v4f x1 = *(const v4f*)(pg + j * 128 + c * 8 + 4);
    bf8 pk;
    pk[0] = (short)f2bf(x0.x); pk[1] = (short)f2bf(x0.y);
    pk[2] = (short)f2bf(x0.z); pk[3] = (short)f2bf(x0.w);
    pk[4] = (short)f2bf(x1.x); pk[5] = (short)f2bf(x1.y);
    pk[6] = (short)f2bf(x1.z); pk[7] = (short)f2bf(x1.w);
    *(bf8*)&pS[j * 128 + ((c ^ (j & 15)) * 8)] = pk;
  }
  __syncthreads();

  // MFMA: W_L * (pair @ W_b) -> lgL[j][h]
  {
    v4f acc = {0.f, 0.f, 0.f, 0.f};
#pragma unroll
    for (int ks = 0; ks < 4; ks++) {
      int slot = (ks * 4 + (l >> 4)) ^ (l & 15);
      bf8 af = *(const bf8*)&pS[(w * 16 + (l & 15)) * 128 + slot * 8];
      acc = __builtin_amdgcn_mfma_f32_16x16x32_bf16(af, wb[ks], acc, 0, 0, 0);
    }
    int h = l & 15;
    if (h < 12) {
#pragma unroll
      for (int r = 0; r < 4; r++)
        lgL[(w * 16 + (l >> 4) * 4 + r) * 15 + h] = acc[r];
    }
  }
  __syncthreads();

  // qk + point-dist terms in f32 (k-side from L2)
  {
    const int j = t >> 2, hg = t & 3;
    const int jg = jt * 64 + j;
#pragma unroll
    for (int hh = 0; hh < 3; hh++) {
      int h = hg * 3 + hh;
      const v4f* kk = (const v4f*)(kbuf + (size_t)jg * 192 + h * 16);
      const v4f* qq = (const v4f*)&qL[h * 16];
      float qk = dot4(kk[0], qq[0]) + dot4(kk[1], qq[1]) +
                 dot4(kk[2], qq[2]) + dot4(kk[3], qq[3]);
      const v4f* kg = (const v4f*)(kgbuf + (size_t)jg * 144 + h * 12);
      const v4f* qg = (const v4f*)&qgL[h * 12];
      float cr = dot4(kg[0], qg[0]) + dot4(kg[1], qg[1]) + dot4(kg[2], qg[2]);
      float sk = skbuf[(size_t)jg * 12 + h];
      lgL[j * 15 + h] += 0.25f * W_L_ * qk + c1L[h] * (cr - 0.5f * sk) + c2L[h];
    }
  }
  __syncthreads();

  // write logits [i][h][jt*64+j], coalesced in j
#pragma unroll
  for (int s = 0; s < 3; s++) {
    int o = t + 256 * s;
    int h = o >> 6, j = o & 63;
    logits[((size_t)i * 12 + h) * 768 + jt * 64 + j] = lgL[j * 15 + h];
  }

  // tail: bf16 pair copy from LDS (no barrier after; drains at endpgm)
  u16* pbg = pair_bf + ((size_t)i * 768 + jt * 64) * 128;
#pragma unroll
  for (int it = 0; it < 4; it++) {
    int idx = t + 256 * it;
    int j = idx >> 4, c = idx & 15;
    bf8 pk = *(const bf8*)&pS[j * 128 + ((c ^ (j & 15)) * 8)];
    *(bf8*)(pbg + j * 128 + c * 8) = pk;
  }
}

// ---------------------------------------------------------------------------
// Pair pass 2 with FUSED softmax. Block per i:
//  A: load logits 12x768 f32 -> LDS; prefetch pair tile 0 to regs
//  B: wave-parallel softmax (wave w owns rows 3w..3w+2, values in regs);
//     writes attn bf16 to global (for ovfin)
//  C: attn bf16 -> LDS slab (full rows); o_pair accumulation over 12 tiles,
//     indexing attn at jt*64+jj
//  D: cross-wave reduction (overlay) -> feats[:,0:1536]
// ---------------------------------------------------------------------------
__global__ __launch_bounds__(256) void opair_sm_k(
    const u16* __restrict__ pair_bf, const float* __restrict__ logits,
    u16* __restrict__ attn, u16* __restrict__ feats_bf) {
  const int i = blockIdx.x, t = threadIdx.x;
  const int w = t >> 6, l = t & 63;
  const int dq = l & 31, hh = l >> 5;
  __shared__ float mem[9216];            // 36.9 KB
  float* aLf = mem;                      // phase A/B: logits f32 [12][768]
  u16* aBf = (u16*)mem;                  // phase C: attn bf16 [12][768] (18.4 KB)
  u16* pS = (u16*)mem + 9216;            // phase C: swizzled pair tile (16 KB)
  float* red = mem;                      // phase D: reduction overlay (24.6 KB)

  // prefetch pair tile 0
  bf8 pr[4];
  const u16* pgb = pair_bf + (size_t)i * 98304;
#pragma unroll
  for (int it = 0; it < 4; it++) {
    int idx = t + 256 * it;
    pr[it] = *(const bf8*)(pgb + (idx >> 4) * 128 + (idx & 15) * 8);
  }
  // A: load logits slab
  const v4f* lg = (const v4f*)(logits + (size_t)i * 9216);
#pragma unroll
  for (int q = 0; q < 9; q++) {
    int idx = t + 256 * q;
    *(v4f*)&aLf[idx * 4] = lg[idx];
  }
  __syncthreads();

  // B: softmax, 3 rows per wave, keep normalized p in regs
  v4f p0[3], p1[3], p2[3];
#pragma unroll
  for (int r = 0; r < 3; r++) {
    const int h = w * 3 + r;
    const float* row = &aLf[h * 768];
    v4f x0 = *(const v4f*)&row[l * 4];
    v4f x1 = *(const v4f*)&row[256 + l * 4];
    v4f x2 = *(const v4f*)&row[512 + l * 4];
    float m0 = fmaxf(fmaxf(x0.x, x0.y), fmaxf(x0.z, x0.w));
    float m1 = fmaxf(fmaxf(x1.x, x1.y), fmaxf(x1.z, x1.w));
    float m2 = fmaxf(fmaxf(x2.x, x2.y), fmaxf(x2.z, x2.w));
    float m = fmaxf(m0, fmaxf(m1, m2));
#pragma unroll
    for (int s = 32; s >= 1; s >>= 1) m = fmaxf(m, __shfl_xor(m, s));
    x0.x = __expf(x0.x - m); x0.y = __expf(x0.y - m);
    x0.z = __expf(x0.z - m); x0.w = __expf(x0.w - m);
    x1.x = __expf(x1.x - m); x1.y = __expf(x1.y - m);
    x1.z = __expf(x1.z - m); x1.w = __expf(x1.w - m);
    x2.x = __expf(x2.x - m); x2.y = __expf(x2.y - m);
    x2.z = __expf(x2.z - m); x2.w = __expf(x2.w - m);
    float ss = x0.x + x0.y + x0.z + x0.w + x1.x + x1.y + x1.z + x1.w +
               x2.x + x2.y + x2.z + x2.w;
#pragma unroll
    for (int q = 32; q >= 1; q >>= 1) ss += __shfl_xor(ss, q);
    float inv = 1.f / ss;
    p0[r] = x0 * inv; p1[r] = x1 * inv; p2[r] = x2 * inv;
    // write global attn (bf16) for ovfin_k
    u16* arow = attn + ((size_t)i * 12 + h) * 768;
    uint2 pk;
    pk.x = (unsigned)f2bf(p0[r].x) | ((unsigned)f2bf(p0[r].y) << 16);
    pk.y = (unsigned)f2bf(p0[r].z) | ((unsigned)f2bf(p0[r].w) << 16);
    *(uint2*)&arow[l * 4] = pk;
    pk.x = (unsigned)f2bf(p1[r].x) | ((unsigned)f2bf(p1[r].y) << 16);
    pk.y = (unsigned)f2bf(p1[r].z) | ((unsigned)f2bf(p1[r].w) << 16);
    *(uint2*)&arow[256 + l * 4] = pk;
    pk.x = (unsigned)f2bf(p2[r].x) | ((unsigned)f2bf(p2[r].y) << 16);
    pk.y = (unsigned)f2bf(p2[r].z) | ((unsigned)f2bf(p2[r].w) << 16);
    *(uint2*)&arow[512 + l * 4] = pk;
  }
  __syncthreads();  // aLf dead beyond this point

  // C-prep: attn bf16 -> LDS slab (full rows)
#pragma unroll
  for (int r = 0; r < 3; r++) {
    const int h = w * 3 + r;
    u16* brow = &aBf[h * 768];
    uint2 pk;
    pk.x = (unsigned)f2bf(p0[r].x) | ((unsigned)f2bf(p0[r].y) << 16);
    pk.y = (unsigned)f2bf(p0[r].z) | ((unsigned)f2bf(p0[r].w) << 16);
    *(uint2*)&brow[l * 4] = pk;
    pk.x = (unsigned)f2bf(p1[r].x) | ((unsigned)f2bf(p1[r].y) << 16);
    pk.y = (unsigned)f2bf(p1[r].z) | ((unsigned)f2bf(p1[r].w) << 16);
    *(uint2*)&brow[256 + l * 4] = pk;
    pk.x = (unsigned)f2bf(p2[r].x) | ((unsigned)f2bf(p2[r].y) << 16);
    pk.y = (unsigned)f2bf(p2[r].z) | ((unsigned)f2bf(p2[r].w) << 16);
    *(uint2*)&brow[512 + l * 4] = pk;
  }

  v4f acc[6];
#pragma unroll
  for (int k = 0; k < 6; k++) acc[k] = (v4f){0.f, 0.f, 0.f, 0.f};

  // C: o_pair accumulation over 12 tiles
  for (int jt = 0; jt < 12; jt++) {
#pragma unroll
    for (int it = 0; it < 4; it++) {
      int idx = t + 256 * it;
      int j = idx >> 4, c = idx & 15;
      *(bf8*)&pS[j * 128 + ((c ^ (j & 15)) * 8)] = pr[it];
    }
    if (jt < 11) {
      const u16* pg = pair_bf + (size_t)i * 98304 + (jt + 1) * 8192;
#pragma unroll
      for (int it = 0; it < 4; it++) {
        int idx = t + 256 * it;
        pr[it] = *(const bf8*)(pg + (idx >> 4) * 128 + (idx & 15) * 8);
      }
    }
    __syncthreads();
    const int jb = jt * 64;
#pragma unroll
    for (int jj16 = 0; jj16 < 16; jj16++) {
      int jj = w * 16 + jj16;
      const u16* pv4 = &pS[jj * 128 + (((dq >> 1) ^ (jj & 15)) * 8) + (dq & 1) * 4];
      v4f pv;
      pv.x = bf2f(pv4[0]); pv.y = bf2f(pv4[1]);
      pv.z = bf2f(pv4[2]); pv.w = bf2f(pv4[3]);
      float a0 = bf2f(aBf[(hh * 6 + 0) * 768 + jb + jj]);
      float a1 = bf2f(aBf[(hh * 6 + 1) * 768 + jb + jj]);
      float a2 = bf2f(aBf[(hh * 6 + 2) * 768 + jb + jj]);
      float a3 = bf2f(aBf[(hh * 6 + 3) * 768 + jb + jj]);
      float a4 = bf2f(aBf[(hh * 6 + 4) * 768 + jb + jj]);
      float a5 = bf2f(aBf[(hh * 6 + 5) * 768 + jb + jj]);
      acc[0] += pv * a0; acc[1] += pv * a1; acc[2] += pv * a2;
      acc[3] += pv * a3; acc[4] += pv * a4; acc[5] += pv * a5;
    }
    __syncthreads();
  }
  // D: cross-wave reduction
#pragma unroll
  for (int k = 0; k < 6; k++)
    *(v4f*)&red[(w * 12 + hh * 6 + k) * 128 + dq * 4] = acc[k];
  __syncthreads();
  const size_t fb = (size_t)i * 2112;
#pragma unroll
  for (int s = 0; s < 6; s++) {
    int o = t + 256 * s;
    int ho = o >> 7, dd = o & 127;
    float v = red[ho * 128 + dd] + red[(12 + ho) * 128 + dd] +
              red[(24 + ho) * 128 + dd] + red[(36 + ho) * 128 + dd];
    feats_bf[fb + o] = f2bf(v);
  }
}

// ---------------------------------------------------------------------------
// o / og + finalize fused: per (i-tile of 64, h).
// ---------------------------------------------------------------------------
__global__ __launch_bounds__(256) void ovfin_k(
    const u16* __restrict__ attn, const float* __restrict__ v2buf,
    const float* __restrict__ fR, const float* __restrict__ ft,
    u16* __restrict__ feats_bf) {
  const int i0 = blockIdx.x * 64, h = blockIdx.y, t = threadIdx.x;
  __shared__ float AL[64][65];
  __shared__ float VL[64][48];
  const int il = t & 63, eb = (t >> 6) * 12;
  v4f acc0 = {0.f, 0.f, 0.f, 0.f}, acc1 = {0.f, 0.f, 0.f, 0.f},
      acc2 = {0.f, 0.f, 0.f, 0.f};
  for (int jt = 0; jt < 12; ++jt) {
    const int j0 = jt * 64;
#pragma unroll
    for (int q = 0; q < 2; q++) {
      int idx = t + 256 * q;
      int ii = idx >> 3, c = idx & 7;
      bf8 av = *(const bf8*)(attn + ((size_t)(i0 + ii) * 12 + h) * 768 + j0 + c * 8);
#pragma unroll
      for (int e = 0; e < 8; e++) AL[ii][c * 8 + e] = bf2f((u16)av[e]);
    }
#pragma unroll
    for (int q = 0; q < 3; q++) {
      int idx = t + q * 256;
      if (idx < 640) {
        int jj = idx / 10, e4 = idx % 10;
        *(v4f*)&VL[jj][e4 * 4] =
            *(const v4f*)(v2buf + (size_t)(j0 + jj) * 480 + h * 40 + e4 * 4);
      }
    }
    __syncthreads();
#pragma unroll 4
    for (int jj = 0; jj < 64; ++jj) {
      float a = AL[il][jj];
      v4f v0 = *(const v4f*)&VL[jj][eb];
      v4f v1 = *(const v4f*)&VL[jj][eb + 4];
      v4f v2 = *(const v4f*)&VL[jj][eb + 8];
      acc0 += v0 * a;
      acc1 += v1 * a;
      acc2 += v2 * a;
    }
    __syncthreads();
  }
  float* OL = &AL[0][0];  // [64][44] overlay
#pragma unroll
  for (int s = 0; s < 12; ++s) {
    int e = eb + s;
    if (e < 40) {
      float v = (s < 4) ? ((float*)&acc0)[s]
                        : (s < 8) ? ((float*)&acc1)[s - 4] : ((float*)&acc2)[s - 8];
      OL[il * 44 + e] = v;
    }
  }
  __syncthreads();
  {
    const int ii = t >> 2, sub = t & 3;
    const int ig = i0 + ii;
    const float* orow = &OL[ii * 44];
    const size_t fb = (size_t)ig * 2112;
    if (sub == 0) {
#pragma unroll
      for (int c = 0; c < 16; c++)
        feats_bf[fb + 1536 + h * 16 + c] = f2bf(orow[c]);
    } else {
      float R[9], tt[3];
#pragma unroll
      for (int k = 0; k < 9; k++) R[k] = fR[ig * 9 + k];
#pragma unroll
      for (int k = 0; k < 3; k++) tt[k] = ft[ig * 3 + k];
      int p0 = (sub - 1) * 3, pn = (sub == 3) ? 2 : 3;
#pragma unroll
      for (int pp = 0; pp < 3; pp++) {
        if (pp < pn) {
          int p = p0 + pp;
          float og0 = orow[16 + p * 3 + 0] - tt[0];
          float og1 = orow[16 + p * 3 + 1] - tt[1];
          float og2 = orow[16 + p * 3 + 2] - tt[2];
          float o0 = R[0] * og0 + R[3] * og1 + R[6] * og2;
          float o1 = R[1] * og0 + R[4] * og1 + R[7] * og2;
          float o2 = R[2] * og0 + R[5] * og1 + R[8] * og2;
          feats_bf[fb + 1728 + h * 24 + p * 3 + 0] = f2bf(o0);
          feats_bf[fb + 1728 + h * 24 + p * 3 + 1] = f2bf(o1);
          feats_bf[fb + 1728 + h * 24 + p * 3 + 2] = f2bf(o2);
          feats_bf[fb + 2016 + h * 8 + p] =
              f2bf(sqrtf(o0 * o0 + o1 * o1 + o2 * o2 + 1e-8f));
        }
      }
    }
  }
}

// ---------------------------------------------------------------------------
extern "C" void kernel_launch(void* const* d_in, const int* in_sizes, int n_in,
                              void* d_out, int out_size, void* d_ws, size_t ws_size,
                              hipStream_t stream) {
  const float* single = (const float*)d_in[0];
  const float* pair = (const float*)d_in[1];
  const float* fR = (const float*)d_in[2];
  const float* ft = (const float*)d_in[3];
  const float* W_qkv = (const float*)d_in[4];
  const float* W_b = (const float*)d_in[5];
  const float* W_qkp = (const float*)d_in[6];
  const float* W_vp = (const float*)d_in[7];
  const float* gamma = (const float*)d_in[8];
  const float* W_out = (const float*)d_in[9];
  const float* b_out = (const float*)d_in[10];
  float* out = (float*)d_out;

  float* ws = (float*)d_ws;
  float* projAll = ws;                      // 884736 (768*1152)
  float* qbuf    = ws + 884736;             // 147456
  float* kbuf    = ws + 1032192;            // 147456
  float* v2buf   = ws + 1179648;            // 368640
  float* qgbuf   = ws + 1548288;            // 110592
  float* kgbuf   = ws + 1658880;            // 110592
  float* sqbuf   = ws + 1769472;            // 9216
  float* skbuf   = ws + 1778688;            // 9216
  float* logits  = ws + 1787904;            // 7077888
  u16* ub        = (u16*)(ws + 8865792);
  u16* single_bf = ub;                      // 294912
  u16* WallFrag  = ub + 294912;             // 442368
  u16* WbFrag    = ub + 737280;             // 2048
  u16* WoutFrag  = ub + 739328;             // 811008
  u16* attn      = ub + 1550336;            // 7077888
  u16* feats_bf  = ub + 8628224;            // 1622016
  u16* pair_bf   = ub + 10250240;           // 75497472

  // fused conversions + weight fragmenting (1 launch)
  wfrag_all<<<250, 256, 0, stream>>>(single, single_bf, W_qkv, W_qkp, W_vp,
                                     W_b, W_out, WallFrag, WbFrag, WoutFrag);
  // all projections in one MFMA GEMM (N = 1152)
  mfma_gemm<<<dim3(36, 12), 256, 0, stream>>>(single_bf, WallFrag, nullptr,
                                              projAll, 768, 1152, 384, 1152);
  // reshape + frames
  prep_kernel<<<768, 256, 0, stream>>>(projAll, fR, ft, qbuf, kbuf, v2buf,
                                       qgbuf, kgbuf, sqbuf, skbuf);
  // pair pass 1: bias MFMA + logits (+ tail bf16 pair copy)
  biaslogit_k<<<dim3(12, 768), 256, 0, stream>>>(pair, WbFrag, gamma, qbuf, kbuf,
                                                 qgbuf, kgbuf, sqbuf, skbuf,
                                                 pair_bf, logits);
  // pair pass 2: fused softmax + o_pair (writes attn bf16 for ovfin)
  opair_sm_k<<<768, 256, 0, stream>>>(pair_bf, logits, attn, feats_bf);
  // o / og + finalize
  ovfin_k<<<dim3(12, 12), 256, 0, stream>>>(attn, v2buf, fR, ft, feats_bf);
  // output projection (bf16 MFMA)
  mfma_gemm<<<dim3(12, 12), 256, 0, stream>>>(feats_bf, WoutFrag, b_out,
                                              out, 768, 384, 2112, 384);
}